// Round 13
// baseline (949.869 us; speedup 1.0000x reference)
//
#include <hip/hip_runtime.h>
#include <hip/hip_fp16.h>

#define HW    512
#define NPIX  (HW*HW)
#define IMGS  32
#define NTOT  (IMGS*NPIX)

// fused-iteration tile: 64x32 output, halo 10 (5 layers x 2)
#define TLW 64
#define TLH 32
#define SW  84   // 64 + 20
#define SH  52   // 32 + 20
#define SA  84   // physical LDS row stride (floats)

// prep tile (normalize + Yc precompute): 64x64, halo 2
#define PT  64
#define PS  68

typedef float v2f __attribute__((ext_vector_type(2)));
typedef float v4f __attribute__((ext_vector_type(4)));

__device__ __forceinline__ float wave_reduce_sum(float v) {
    #pragma unroll
    for (int off = 32; off > 0; off >>= 1) v += __shfl_down(v, off);
    return v;
}

__device__ __forceinline__ float2 h2tof2(unsigned u) {
    __half2 h = *reinterpret_cast<const __half2*>(&u);
    return __half22float2(h);
}

// ---------------- prologue: global min-max ----------------
__global__ __launch_bounds__(256) void minmax_partial(
    const float4* __restrict__ x, float* __restrict__ pmin, float* __restrict__ pmax)
{
    const int n4 = NTOT / 4;
    int tid = threadIdx.x + blockIdx.x * 256;
    int stride = gridDim.x * 256;
    float mn = 3.402823466e38f, mx = -3.402823466e38f;
    for (int i = tid; i < n4; i += stride) {
        float4 v = x[i];
        mn = fminf(mn, fminf(fminf(v.x, v.y), fminf(v.z, v.w)));
        mx = fmaxf(mx, fmaxf(fmaxf(v.x, v.y), fmaxf(v.z, v.w)));
    }
    #pragma unroll
    for (int off = 32; off > 0; off >>= 1) {
        mn = fminf(mn, __shfl_down(mn, off));
        mx = fmaxf(mx, __shfl_down(mx, off));
    }
    __shared__ float smn[4], smx[4];
    int lane = threadIdx.x & 63, wid = threadIdx.x >> 6;
    if (lane == 0) { smn[wid] = mn; smx[wid] = mx; }
    __syncthreads();
    if (threadIdx.x == 0) {
        mn = fminf(fminf(smn[0], smn[1]), fminf(smn[2], smn[3]));
        mx = fmaxf(fmaxf(smx[0], smx[1]), fmaxf(smx[2], smx[3]));
        pmin[blockIdx.x] = mn;
        pmax[blockIdx.x] = mx;
    }
}

__global__ __launch_bounds__(256) void minmax_final(
    const float* __restrict__ pmin, const float* __restrict__ pmax,
    float* __restrict__ scal, int nparts)
{
    float mn = 3.402823466e38f, mx = -3.402823466e38f;
    for (int i = threadIdx.x; i < nparts; i += 256) {
        mn = fminf(mn, pmin[i]);
        mx = fmaxf(mx, pmax[i]);
    }
    #pragma unroll
    for (int off = 32; off > 0; off >>= 1) {
        mn = fminf(mn, __shfl_down(mn, off));
        mx = fmaxf(mx, __shfl_down(mx, off));
    }
    __shared__ float smn[4], smx[4];
    int lane = threadIdx.x & 63, wid = threadIdx.x >> 6;
    if (lane == 0) { smn[wid] = mn; smx[wid] = mx; }
    __syncthreads();
    if (threadIdx.x == 0) {
        mn = fminf(fminf(smn[0], smn[1]), fminf(smn[2], smn[3]));
        mx = fmaxf(fmaxf(smx[0], smx[1]), fmaxf(smx[2], smx[3]));
        scal[0] = mn;
        scal[1] = 1.0f / (mx - mn);
    }
}

__global__ __launch_bounds__(256) void normalize_k(
    const float4* __restrict__ x, float4* __restrict__ y, const float* __restrict__ scal)
{
    const int n4 = NTOT / 4;
    float mn = scal[0], inv = scal[1];
    int tid = threadIdx.x + blockIdx.x * 256;
    int stride = gridDim.x * 256;
    for (int i = tid; i < n4; i += stride) {
        float4 v = x[i];
        v.x = (v.x - mn) * inv;
        v.y = (v.y - mn) * inv;
        v.z = (v.z - mn) * inv;
        v.w = (v.w - mn) * inv;
        y[i] = v;
    }
}

// ---- prep: normalize (-> fp16 y16) + precompute Yc[l] = conv(y,Wy[l]) + bx[l]+by[l] (fp16) ----
__global__ __launch_bounds__(256) void prep(
    const float* __restrict__ x, const float* __restrict__ scal,
    const float* __restrict__ bx,
    const float* __restrict__ Wy, const float* __restrict__ by,
    __half* __restrict__ y16, __half* __restrict__ Yc)
{
    __shared__ __align__(16) float ys[PS * PS];   // 68x68 = 18.5 KB

    const int img = blockIdx.z;
    const int tileX = blockIdx.x * PT;
    const int tileY = blockIdx.y * PT;
    const int tid = threadIdx.x;
    const float mn = scal[0], inv = scal[1];
    const float* xim = x + (size_t)img * NPIX;

    // stage normalized y with halo 2; exact 0 outside image (zero padding)
    for (int p = tid; p < PS * PS / 2; p += 256) {
        int row = p / (PS / 2);
        int cp  = p - row * (PS / 2);
        int gr = tileY - 2 + row;
        int gc = tileX - 2 + 2 * cp;
        float a = 0.f, b = 0.f;
        if (((unsigned)gr < HW) & ((unsigned)gc < HW)) {
            float2 v = *(const float2*)(xim + (size_t)gr * HW + gc);
            a = (v.x - mn) * inv;
            b = (v.y - mn) * inv;
        }
        ys[row * PS + 2 * cp]     = a;
        ys[row * PS + 2 * cp + 1] = b;
    }
    __syncthreads();

    // write normalized y tile to global as fp16
    for (int p = tid; p < PT * PT / 2; p += 256) {
        int row = p / (PT / 2);
        int cp  = p - row * (PT / 2);
        float2 v = *(const float2*)&ys[(row + 2) * PS + 2 * cp + 2];
        *(__half2*)(y16 + (size_t)img * NPIX + (size_t)(tileY + row) * HW + tileX + 2 * cp)
            = __floats2half2_rn(v.x, v.y);
    }

    // each thread: 4x4 output block, 5 convs over the staged y window
    const int br = tid >> 4, bc = tid & 15;
    const float* yp = ys + (4 * br) * PS + 4 * bc;

    #pragma unroll
    for (int l = 0; l < 5; ++l) {
        float w[25];
        #pragma unroll
        for (int k = 0; k < 25; ++k) w[k] = Wy[25 * l + k];
        const float bias = bx[l] + by[l];

        float acc[4][4] = {};
        #pragma unroll
        for (int di = 0; di < 8; ++di) {
            float xr[8];
            *(float4*)&xr[0] = *(const float4*)(yp + di * PS);
            *(float4*)&xr[4] = *(const float4*)(yp + di * PS + 4);
            #pragma unroll
            for (int o = 0; o < 4; ++o) {
                const int ki = di - o;
                if (ki >= 0 && ki <= 4) {
                    #pragma unroll
                    for (int kj = 0; kj < 5; ++kj) {
                        const float wa = w[ki * 5 + kj];
                        #pragma unroll
                        for (int j = 0; j < 4; ++j)
                            acc[o][j] = fmaf(xr[kj + j], wa, acc[o][j]);
                    }
                }
            }
        }
        __half* yl = Yc + (size_t)l * NTOT + (size_t)img * NPIX;
        #pragma unroll
        for (int o = 0; o < 4; ++o) {
            __half2* q = (__half2*)(yl + (size_t)(tileY + 4 * br + o) * HW + tileX + 4 * bc);
            q[0] = __floats2half2_rn(acc[o][0] + bias, acc[o][1] + bias);
            q[1] = __floats2half2_rn(acc[o][2] + bias, acc[o][3] + bias);
        }
    }
}

// ---------------- one x-conv layer, IN-PLACE in a single LDS buffer ----------------
// scale (1/prev_sum) is folded into the L0 weights (conv is linear), so the
// staged tile is a pure fp16->fp32 copy of x.
template<int WIN, int HIN, int L, bool LAST>
__device__ __forceinline__ float conv_layer_ip(
    float* __restrict__ buf, const float* __restrict__ Wx, float scale,
    const unsigned (&ycA)[5][4], const unsigned (&ycB)[5][4],
    __half* __restrict__ hout, float* __restrict__ fout,
    int img, int tileX, int tileY)
{
    constexpr int WOUT = WIN - 4, HOUT = HIN - 4;
    constexpr int NBC = WOUT / 4, NBR = HOUT / 4, NB = NBC * NBR;
    const int tid = threadIdx.x;
    const bool active = tid < NB;
    const int br = active ? (tid / NBC) : 0;
    const int bc = active ? (tid - br * NBC) : 0;

    // acc2[o][jp] holds output columns {2jp, 2jp+1} of row o
    v2f acc2[4][2] = {};
    if (active) {
        float w[25];
        #pragma unroll
        for (int k = 0; k < 25; ++k) {
            w[k] = Wx[25 * L + k];
            if constexpr (L == 0) w[k] *= scale;   // fold 1/sum into L0 weights
        }

        const float* xp = buf + (4 * br) * SA + 4 * bc;
        #pragma unroll
        for (int di = 0; di < 8; ++di) {
            const v4f a0 = *(const v4f*)(xp + di * SA);       // ds_read_b128
            const v4f a1 = *(const v4f*)(xp + di * SA + 4);   // ds_read_b128
            v2f pr[7];
            pr[0] = __builtin_shufflevector(a0, a0, 0, 1);
            pr[1] = __builtin_shufflevector(a0, a0, 1, 2);
            pr[2] = __builtin_shufflevector(a0, a0, 2, 3);
            pr[3] = __builtin_shufflevector(a0, a1, 3, 4);
            pr[4] = __builtin_shufflevector(a1, a1, 0, 1);
            pr[5] = __builtin_shufflevector(a1, a1, 1, 2);
            pr[6] = __builtin_shufflevector(a1, a1, 2, 3);
            #pragma unroll
            for (int o = 0; o < 4; ++o) {
                const int ki = di - o;
                if (ki >= 0 && ki <= 4) {   // folds at compile time
                    #pragma unroll
                    for (int kj = 0; kj < 5; ++kj) {
                        const float ww = w[ki * 5 + kj];
                        v2f w2; w2.x = ww; w2.y = ww;
                        acc2[o][0] = __builtin_elementwise_fma(pr[kj],     w2, acc2[o][0]);
                        acc2[o][1] = __builtin_elementwise_fma(pr[kj + 2], w2, acc2[o][1]);
                    }
                }
            }
        }
    }

    if constexpr (!LAST) __syncthreads();   // all reads complete before in-place writes

    const int gy0 = tileY - 8 + 2 * L + 4 * br;   // == tileY + 4*br when L==4
    const int gx0 = tileX - 8 + 2 * L + 4 * bc;

    float bsum = 0.0f;
    if (active) {
        if constexpr (LAST) {
            const size_t base = (size_t)img * NPIX;
            #pragma unroll
            for (int o = 0; o < 4; ++o) {
                float2 u = h2tof2(ycA[L][o]);
                float2 t = h2tof2(ycB[L][o]);
                float4 v;
                v.x = fmaxf(acc2[o][0].x + u.x, 0.0f);
                v.y = fmaxf(acc2[o][0].y + u.y, 0.0f);
                v.z = fmaxf(acc2[o][1].x + t.x, 0.0f);
                v.w = fmaxf(acc2[o][1].y + t.y, 0.0f);
                const size_t idx = base + (size_t)(gy0 + o) * HW + gx0;
                if (fout) {                              // iteration 9: fp32 d_out
                    *(float4*)(fout + idx) = v;
                } else {                                 // iterations 0-8: fp16 ping-pong
                    __half2* q = (__half2*)(hout + idx);
                    q[0] = __floats2half2_rn(v.x, v.y);
                    q[1] = __floats2half2_rn(v.z, v.w);
                }
                bsum += (v.x + v.y) + (v.z + v.w);
            }
        } else {
            bool cok[4];
            #pragma unroll
            for (int j = 0; j < 4; ++j) cok[j] = (unsigned)(gx0 + j) < HW;
            #pragma unroll
            for (int o = 0; o < 4; ++o) {
                const bool rok = (unsigned)(gy0 + o) < HW;
                float2 u = h2tof2(ycA[L][o]);
                float2 t = h2tof2(ycB[L][o]);
                v4f v;
                v.x = (rok && cok[0]) ? fmaxf(acc2[o][0].x + u.x, 0.0f) : 0.0f;
                v.y = (rok && cok[1]) ? fmaxf(acc2[o][0].y + u.y, 0.0f) : 0.0f;
                v.z = (rok && cok[2]) ? fmaxf(acc2[o][1].x + t.x, 0.0f) : 0.0f;
                v.w = (rok && cok[3]) ? fmaxf(acc2[o][1].y + t.y, 0.0f) : 0.0f;
                *(v4f*)(buf + (4 * br + o) * SA + 4 * bc) = v;   // ds_write_b128
            }
        }
    }

    if constexpr (!LAST) __syncthreads();   // writes visible before next layer reads
    (void)img;
    return bsum;
}

// ---------------- fused 5-layer iteration kernel (single LDS buffer) ----------------
// __launch_bounds__(256, 6): empirically the 2nd arg == co-resident 256-thread
// blocks/CU (R2:3->31%, R9/R11:4->36%, R10:8->74%, unspecified R12: behaves
// like 4). N=6 gives VGPR budget 512/6=85 >= natural 52 -> no spill (R10's
// N=8 capped at 64 and the allocator collapsed to 32 + scratch). LDS
// 6 x 17.9KB = 107KB <= 160KB.
__global__ __launch_bounds__(256, 6) void fused5_yc(
    const __half* __restrict__ xin, const float* __restrict__ Wx,
    const __half* __restrict__ Ych, const float* __restrict__ sum_prev,
    __half* __restrict__ hout, float* __restrict__ fout,
    float* __restrict__ sum_out)
{
    __shared__ __align__(16) float Xa[SA * SH];   // 84x52 = 17.5 KB

    const int img = blockIdx.z;
    const int tileX = blockIdx.x * TLW;
    const int tileY = blockIdx.y * TLH;
    const int tid = threadIdx.x;

    const float scale = sum_prev ? (1.0f / sum_prev[0]) : 1.0f;
    const __half* xim = xin + (size_t)img * NPIX;
    const __half* ycb = Ych + (size_t)img * NPIX;
    const size_t PL = (size_t)IMGS * NPIX;

    // ---- stage x (fp16 in) with halo 10, pure copy (scale folded into L0 weights) ----
    constexpr int NPAIR = SW * SH / 2;   // 2184
    for (int p = tid; p < NPAIR; p += 256) {
        int row = p / (SW / 2);
        int cp  = p - row * (SW / 2);
        int gr = tileY - 10 + row;
        int gc = tileX - 10 + 2 * cp;
        unsigned u = 0u;
        if (((unsigned)gr < HW) & ((unsigned)gc < HW))
            u = *(const unsigned*)(xim + (size_t)gr * HW + gc);
        float2 f = h2tof2(u);
        v2f fv; fv.x = f.x; fv.y = f.y;
        *(v2f*)&Xa[2 * p] = fv;                         // ds_write_b64
    }

    // ---- upfront Yc prefetch: all 5 layers into registers (fp16, 2 dwords/row).
    // One latency event: everything drains at the first barrier. ----
    unsigned ycA[5][4], ycB[5][4];
    {
        const int NBCs[5] = {20, 19, 18, 17, 16};
        #pragma unroll
        for (int l = 0; l < 5; ++l) {
            const int br = tid / NBCs[l], bc = tid - br * NBCs[l];
            const int gy0 = tileY - 8 + 2 * l + 4 * br;
            const int gx0 = tileX - 8 + 2 * l + 4 * bc;   // always even
            const __half* pl = ycb + (ptrdiff_t)l * PL;
            #pragma unroll
            for (int o = 0; o < 4; ++o) {
                const __half* p = pl + (ptrdiff_t)(gy0 + o) * HW + gx0;
                ycA[l][o] = *(const unsigned*)(p);
                ycB[l][o] = *(const unsigned*)(p + 2);
            }
        }
    }
    __syncthreads();

    conv_layer_ip<84, 52, 0, false>(Xa, Wx, scale, ycA, ycB, nullptr, nullptr, img, tileX, tileY);
    conv_layer_ip<80, 48, 1, false>(Xa, Wx, scale, ycA, ycB, nullptr, nullptr, img, tileX, tileY);
    conv_layer_ip<76, 44, 2, false>(Xa, Wx, scale, ycA, ycB, nullptr, nullptr, img, tileX, tileY);
    conv_layer_ip<72, 40, 3, false>(Xa, Wx, scale, ycA, ycB, nullptr, nullptr, img, tileX, tileY);
    float bs = conv_layer_ip<68, 36, 4, true>(Xa, Wx, scale, ycA, ycB, hout, fout, img, tileX, tileY);

    bs = wave_reduce_sum(bs);
    __shared__ float ssum[4];
    if ((tid & 63) == 0) ssum[tid >> 6] = bs;
    __syncthreads();
    if (tid == 0)
        atomicAdd(sum_out, (ssum[0] + ssum[1]) + (ssum[2] + ssum[3]));
}

__global__ __launch_bounds__(256) void final_scale_raw(
    float4* __restrict__ io, const float* __restrict__ sum9)
{
    const int n4 = NTOT / 4;
    const float s = 1.0f / sum9[0];
    int tid = threadIdx.x + blockIdx.x * 256;
    int stride = gridDim.x * 256;
    for (int i = tid; i < n4; i += stride) {
        float4 v = io[i];
        v.x *= s; v.y *= s; v.z *= s; v.w *= s;
        io[i] = v;
    }
}

// ---------------- fallback: round-2/3 dual-conv fused kernel ----------------
template<int WIN, int HIN, int L, bool LAST>
__device__ __forceinline__ float conv_layer(
    const float* __restrict__ inb, float* __restrict__ outb,
    const float* __restrict__ yb,
    const float* __restrict__ Wx, const float* __restrict__ Wy,
    const float* __restrict__ bx, const float* __restrict__ by,
    float* __restrict__ gout, int img, int tileX, int tileY)
{
    constexpr int WOUT = WIN - 4, HOUT = HIN - 4;
    constexpr int NBC = WOUT / 4, NBR = HOUT / 4, NB = NBC * NBR;
    const int tid = threadIdx.x;
    float bsum = 0.0f;
    if (tid < NB) {
        float wxl[25], wyl[25];
        #pragma unroll
        for (int k = 0; k < 25; ++k) {
            wxl[k] = Wx[25 * L + k];
            wyl[k] = Wy[25 * L + k];
        }
        const float bias = bx[L] + by[L];
        const int br = tid / NBC, bc = tid - (tid / NBC) * NBC;
        const float* xp = inb + (4 * br) * WIN + 4 * bc;
        const float* yp = yb + (4 * br + 2 * L) * 84 + 4 * bc + 2 * L;

        float acc[4][4] = {};
        #pragma unroll
        for (int di = 0; di < 8; ++di) {
            float xr[8], yr[8];
            *(float4*)&xr[0] = *(const float4*)(xp + di * WIN);
            *(float4*)&xr[4] = *(const float4*)(xp + di * WIN + 4);
            if constexpr ((L & 1) == 0) {
                *(float4*)&yr[0] = *(const float4*)(yp + di * 84);
                *(float4*)&yr[4] = *(const float4*)(yp + di * 84 + 4);
            } else {
                *(float2*)&yr[0] = *(const float2*)(yp + di * 84);
                *(float4*)&yr[2] = *(const float4*)(yp + di * 84 + 2);
                *(float2*)&yr[6] = *(const float2*)(yp + di * 84 + 6);
            }
            #pragma unroll
            for (int o = 0; o < 4; ++o) {
                const int ki = di - o;
                if (ki >= 0 && ki <= 4) {
                    #pragma unroll
                    for (int kj = 0; kj < 5; ++kj) {
                        const float wa = wxl[ki * 5 + kj];
                        const float wb = wyl[ki * 5 + kj];
                        #pragma unroll
                        for (int j = 0; j < 4; ++j)
                            acc[o][j] = fmaf(xr[kj + j], wa,
                                        fmaf(yr[kj + j], wb, acc[o][j]));
                    }
                }
            }
        }

        if constexpr (LAST) {
            #pragma unroll
            for (int o = 0; o < 4; ++o) {
                float4 v;
                v.x = fmaxf(acc[o][0] + bias, 0.0f);
                v.y = fmaxf(acc[o][1] + bias, 0.0f);
                v.z = fmaxf(acc[o][2] + bias, 0.0f);
                v.w = fmaxf(acc[o][3] + bias, 0.0f);
                float* g = gout + (size_t)img * NPIX +
                           (size_t)(tileY + 4 * br + o) * HW + tileX + 4 * bc;
                *(float4*)g = v;
                bsum += (v.x + v.y) + (v.z + v.w);
            }
        } else {
            const int gy0 = tileY - 8 + 2 * L + 4 * br;
            const int gx0 = tileX - 8 + 2 * L + 4 * bc;
            bool cok[4];
            #pragma unroll
            for (int j = 0; j < 4; ++j) cok[j] = (unsigned)(gx0 + j) < HW;
            #pragma unroll
            for (int o = 0; o < 4; ++o) {
                const bool rok = (unsigned)(gy0 + o) < HW;
                float4 v;
                v.x = (rok && cok[0]) ? fmaxf(acc[o][0] + bias, 0.0f) : 0.0f;
                v.y = (rok && cok[1]) ? fmaxf(acc[o][1] + bias, 0.0f) : 0.0f;
                v.z = (rok && cok[2]) ? fmaxf(acc[o][2] + bias, 0.0f) : 0.0f;
                v.w = (rok && cok[3]) ? fmaxf(acc[o][3] + bias, 0.0f) : 0.0f;
                *(float4*)(outb + (4 * br + o) * WOUT + 4 * bc) = v;
            }
        }
    }
    (void)img; (void)gout;
    return bsum;
}

__global__ __launch_bounds__(256, 3) void fused5(
    const float* __restrict__ xin, const float* __restrict__ yin,
    const float* __restrict__ Wx, const float* __restrict__ bx,
    const float* __restrict__ Wy, const float* __restrict__ by,
    const float* __restrict__ scale_p,
    float* __restrict__ gout, float* __restrict__ spart)
{
    __shared__ __align__(16) float Xa[84 * 52];
    __shared__ __align__(16) float Xb[80 * 48];
    __shared__ __align__(16) float Yb[84 * 52];

    const int img = blockIdx.z;
    const int tileX = blockIdx.x * TLW;
    const int tileY = blockIdx.y * TLH;
    const int tid = threadIdx.x;

    const float scale = scale_p ? scale_p[0] : 1.0f;
    const float* xim = xin + (size_t)img * NPIX;
    const float* yim = yin + (size_t)img * NPIX;

    constexpr int NPAIR = 84 * 52 / 2;
    for (int p = tid; p < NPAIR; p += 256) {
        int row = p / 42;
        int cp  = p - row * 42;
        int gr = tileY - 10 + row;
        int gc = tileX - 10 + 2 * cp;
        float2 xv = make_float2(0.f, 0.f), yv = make_float2(0.f, 0.f);
        if (((unsigned)gr < HW) & ((unsigned)gc < HW)) {
            xv = *(const float2*)(xim + (size_t)gr * HW + gc);
            yv = *(const float2*)(yim + (size_t)gr * HW + gc);
        }
        Xa[2 * p]     = xv.x * scale;
        Xa[2 * p + 1] = xv.y * scale;
        *(float2*)&Yb[2 * p] = yv;
    }
    __syncthreads();

    conv_layer<84, 52, 0, false>(Xa, Xb, Yb, Wx, Wy, bx, by, nullptr, img, tileX, tileY);
    __syncthreads();
    conv_layer<80, 48, 1, false>(Xb, Xa, Yb, Wx, Wy, bx, by, nullptr, img, tileX, tileY);
    __syncthreads();
    conv_layer<76, 44, 2, false>(Xa, Xb, Yb, Wx, Wy, bx, by, nullptr, img, tileX, tileY);
    __syncthreads();
    conv_layer<72, 40, 3, false>(Xb, Xa, Yb, Wx, Wy, bx, by, nullptr, img, tileX, tileY);
    __syncthreads();
    float bs = conv_layer<68, 36, 4, true>(Xa, nullptr, Yb, Wx, Wy, bx, by, gout, img, tileX, tileY);

    bs = wave_reduce_sum(bs);
    __shared__ float ssum[4];
    if ((tid & 63) == 0) ssum[tid >> 6] = bs;
    __syncthreads();
    if (tid == 0) {
        int b = (blockIdx.z * gridDim.y + blockIdx.y) * gridDim.x + blockIdx.x;
        spart[b] = (ssum[0] + ssum[1]) + (ssum[2] + ssum[3]);
    }
}

__global__ __launch_bounds__(256) void reduce_sum(
    const float* __restrict__ p, int n, float* __restrict__ invS)
{
    float s = 0.0f;
    for (int i = threadIdx.x; i < n; i += 256) s += p[i];
    s = wave_reduce_sum(s);
    __shared__ float sh[4];
    int lane = threadIdx.x & 63, wid = threadIdx.x >> 6;
    if (lane == 0) sh[wid] = s;
    __syncthreads();
    if (threadIdx.x == 0) invS[0] = 1.0f / ((sh[0] + sh[1]) + (sh[2] + sh[3]));
}

__global__ __launch_bounds__(256) void final_scale(
    float4* __restrict__ io, const float* __restrict__ invS)
{
    const int n4 = NTOT / 4;
    const float s = invS[0];
    int tid = threadIdx.x + blockIdx.x * 256;
    int stride = gridDim.x * 256;
    for (int i = tid; i < n4; i += stride) {
        float4 v = io[i];
        v.x *= s; v.y *= s; v.z *= s; v.w *= s;
        io[i] = v;
    }
}

extern "C" void kernel_launch(void* const* d_in, const int* in_sizes, int n_in,
                              void* d_out, int out_size, void* d_ws, size_t ws_size,
                              hipStream_t stream)
{
    const float* x  = (const float*)d_in[0];
    const float* Wx = (const float*)d_in[1];
    const float* bx = (const float*)d_in[2];
    const float* Wy = (const float*)d_in[3];
    const float* by = (const float*)d_in[4];
    float* out = (float*)d_out;
    float* ws  = (float*)d_ws;

    // workspace layout (floats)
    float* sums  = ws;             // [0..9] per-iteration atomic sums (zeroed)
    float* scal  = ws + 12;        // [12]=min, [13]=1/(max-min)
    float* invS  = ws + 16;        // 10 slots (fallback path)
    float* pmin  = ws + 64;        // 1024
    float* pmax  = ws + 64 + 1024;
    float* spart = ws + 4096;      // 4096 (fallback path)
    // fp16 region: y16 | xhA | xhB | Ych (5 planes) | guard
    __half* y16 = (__half*)(ws + 16384);
    __half* xhA = y16 + NTOT;
    __half* xhB = xhA + NTOT;
    __half* Ych = xhB + NTOT;      // 5*NTOT halves

    const size_t needYC = ((size_t)16384 + 4ull * NTOT + 16384) * sizeof(float);

    minmax_partial<<<1024, 256, 0, stream>>>((const float4*)x, pmin, pmax);
    minmax_final<<<1, 256, 0, stream>>>(pmin, pmax, scal, 1024);

    if (ws_size >= needYC) {
        hipMemsetAsync(sums, 0, 10 * sizeof(float), stream);

        dim3 pgrid(HW / PT, HW / PT, IMGS);            // (8, 8, 32)
        prep<<<pgrid, 256, 0, stream>>>(x, scal, bx, Wy, by, y16, Ych);

        dim3 grid(HW / TLW, HW / TLH, IMGS);           // (8, 16, 32)
        const __half* cur = y16;
        for (int it = 0; it < 10; ++it) {
            __half* hdst = (it % 2 == 0) ? xhA : xhB;
            float* fdst = (it == 9) ? out : nullptr;   // last iteration -> fp32 d_out
            const float* sum_prev = (it > 0) ? (sums + (it - 1)) : nullptr;
            fused5_yc<<<grid, 256, 0, stream>>>(cur, Wx, Ych, sum_prev, hdst, fdst, sums + it);
            cur = hdst;
        }
        final_scale_raw<<<2048, 256, 0, stream>>>((float4*)out, sums + 9);
    } else {
        // --- fallback: round-2/3 dual-conv path (fp32 throughout) ---
        float* ybuf = ws + 16384;
        float* xAf  = ybuf + NTOT;
        normalize_k<<<2048, 256, 0, stream>>>((const float4*)x, (float4*)ybuf, scal);
        dim3 grid(HW / TLW, HW / TLH, IMGS);
        const float* cur = ybuf;
        for (int it = 0; it < 10; ++it) {
            float* dst = (it % 2 == 0) ? xAf : out;
            const float* scale_p = (it > 0) ? (invS + (it - 1)) : nullptr;
            fused5<<<grid, 256, 0, stream>>>(cur, ybuf, Wx, bx, Wy, by, scale_p, dst, spart);
            reduce_sum<<<1, 256, 0, stream>>>(spart, 4096, invS + it);
            cur = dst;
        }
        final_scale<<<2048, 256, 0, stream>>>((float4*)out, invS + 9);
    }
}

// Round 14
// 779.545 us; speedup vs baseline: 1.2185x; 1.2185x over previous
//
#include <hip/hip_runtime.h>
#include <hip/hip_fp16.h>

#define HW    512
#define NPIX  (HW*HW)
#define IMGS  32
#define NTOT  (IMGS*NPIX)

// fused-iteration tile: 64x32 output, halo 10 (5 layers x 2)
#define TLW 64
#define TLH 32
#define SW  84   // 64 + 20
#define SH  52   // 32 + 20
#define SA  84   // physical LDS row stride (floats)

// prep tile (normalize + Yc precompute): 64x64, halo 2
#define PT  64
#define PS  68

typedef float v2f __attribute__((ext_vector_type(2)));
typedef float v4f __attribute__((ext_vector_type(4)));

__device__ __forceinline__ float wave_reduce_sum(float v) {
    #pragma unroll
    for (int off = 32; off > 0; off >>= 1) v += __shfl_down(v, off);
    return v;
}

__device__ __forceinline__ float2 h2tof2(unsigned u) {
    __half2 h = *reinterpret_cast<const __half2*>(&u);
    return __half22float2(h);
}

// ---------------- prologue: global min-max ----------------
__global__ __launch_bounds__(256) void minmax_partial(
    const float4* __restrict__ x, float* __restrict__ pmin, float* __restrict__ pmax)
{
    const int n4 = NTOT / 4;
    int tid = threadIdx.x + blockIdx.x * 256;
    int stride = gridDim.x * 256;
    float mn = 3.402823466e38f, mx = -3.402823466e38f;
    for (int i = tid; i < n4; i += stride) {
        float4 v = x[i];
        mn = fminf(mn, fminf(fminf(v.x, v.y), fminf(v.z, v.w)));
        mx = fmaxf(mx, fmaxf(fmaxf(v.x, v.y), fmaxf(v.z, v.w)));
    }
    #pragma unroll
    for (int off = 32; off > 0; off >>= 1) {
        mn = fminf(mn, __shfl_down(mn, off));
        mx = fmaxf(mx, __shfl_down(mx, off));
    }
    __shared__ float smn[4], smx[4];
    int lane = threadIdx.x & 63, wid = threadIdx.x >> 6;
    if (lane == 0) { smn[wid] = mn; smx[wid] = mx; }
    __syncthreads();
    if (threadIdx.x == 0) {
        mn = fminf(fminf(smn[0], smn[1]), fminf(smn[2], smn[3]));
        mx = fmaxf(fmaxf(smx[0], smx[1]), fmaxf(smx[2], smx[3]));
        pmin[blockIdx.x] = mn;
        pmax[blockIdx.x] = mx;
    }
}

__global__ __launch_bounds__(256) void minmax_final(
    const float* __restrict__ pmin, const float* __restrict__ pmax,
    float* __restrict__ scal, int nparts)
{
    float mn = 3.402823466e38f, mx = -3.402823466e38f;
    for (int i = threadIdx.x; i < nparts; i += 256) {
        mn = fminf(mn, pmin[i]);
        mx = fmaxf(mx, pmax[i]);
    }
    #pragma unroll
    for (int off = 32; off > 0; off >>= 1) {
        mn = fminf(mn, __shfl_down(mn, off));
        mx = fmaxf(mx, __shfl_down(mx, off));
    }
    __shared__ float smn[4], smx[4];
    int lane = threadIdx.x & 63, wid = threadIdx.x >> 6;
    if (lane == 0) { smn[wid] = mn; smx[wid] = mx; }
    __syncthreads();
    if (threadIdx.x == 0) {
        mn = fminf(fminf(smn[0], smn[1]), fminf(smn[2], smn[3]));
        mx = fmaxf(fmaxf(smx[0], smx[1]), fmaxf(smx[2], smx[3]));
        scal[0] = mn;
        scal[1] = 1.0f / (mx - mn);
    }
}

__global__ __launch_bounds__(256) void normalize_k(
    const float4* __restrict__ x, float4* __restrict__ y, const float* __restrict__ scal)
{
    const int n4 = NTOT / 4;
    float mn = scal[0], inv = scal[1];
    int tid = threadIdx.x + blockIdx.x * 256;
    int stride = gridDim.x * 256;
    for (int i = tid; i < n4; i += stride) {
        float4 v = x[i];
        v.x = (v.x - mn) * inv;
        v.y = (v.y - mn) * inv;
        v.z = (v.z - mn) * inv;
        v.w = (v.w - mn) * inv;
        y[i] = v;
    }
}

// ---- prep: normalize (-> fp16 y16) + precompute Yc[l] = conv(y,Wy[l]) + bx[l]+by[l] (fp16) ----
__global__ __launch_bounds__(256) void prep(
    const float* __restrict__ x, const float* __restrict__ scal,
    const float* __restrict__ bx,
    const float* __restrict__ Wy, const float* __restrict__ by,
    __half* __restrict__ y16, __half* __restrict__ Yc)
{
    __shared__ __align__(16) float ys[PS * PS];   // 68x68 = 18.5 KB

    const int img = blockIdx.z;
    const int tileX = blockIdx.x * PT;
    const int tileY = blockIdx.y * PT;
    const int tid = threadIdx.x;
    const float mn = scal[0], inv = scal[1];
    const float* xim = x + (size_t)img * NPIX;

    // stage normalized y with halo 2; exact 0 outside image (zero padding)
    for (int p = tid; p < PS * PS / 2; p += 256) {
        int row = p / (PS / 2);
        int cp  = p - row * (PS / 2);
        int gr = tileY - 2 + row;
        int gc = tileX - 2 + 2 * cp;
        float a = 0.f, b = 0.f;
        if (((unsigned)gr < HW) & ((unsigned)gc < HW)) {
            float2 v = *(const float2*)(xim + (size_t)gr * HW + gc);
            a = (v.x - mn) * inv;
            b = (v.y - mn) * inv;
        }
        ys[row * PS + 2 * cp]     = a;
        ys[row * PS + 2 * cp + 1] = b;
    }
    __syncthreads();

    // write normalized y tile to global as fp16
    for (int p = tid; p < PT * PT / 2; p += 256) {
        int row = p / (PT / 2);
        int cp  = p - row * (PT / 2);
        float2 v = *(const float2*)&ys[(row + 2) * PS + 2 * cp + 2];
        *(__half2*)(y16 + (size_t)img * NPIX + (size_t)(tileY + row) * HW + tileX + 2 * cp)
            = __floats2half2_rn(v.x, v.y);
    }

    // each thread: 4x4 output block, 5 convs over the staged y window
    const int br = tid >> 4, bc = tid & 15;
    const float* yp = ys + (4 * br) * PS + 4 * bc;

    #pragma unroll
    for (int l = 0; l < 5; ++l) {
        float w[25];
        #pragma unroll
        for (int k = 0; k < 25; ++k) w[k] = Wy[25 * l + k];
        const float bias = bx[l] + by[l];

        float acc[4][4] = {};
        #pragma unroll
        for (int di = 0; di < 8; ++di) {
            float xr[8];
            *(float4*)&xr[0] = *(const float4*)(yp + di * PS);
            *(float4*)&xr[4] = *(const float4*)(yp + di * PS + 4);
            #pragma unroll
            for (int o = 0; o < 4; ++o) {
                const int ki = di - o;
                if (ki >= 0 && ki <= 4) {
                    #pragma unroll
                    for (int kj = 0; kj < 5; ++kj) {
                        const float wa = w[ki * 5 + kj];
                        #pragma unroll
                        for (int j = 0; j < 4; ++j)
                            acc[o][j] = fmaf(xr[kj + j], wa, acc[o][j]);
                    }
                }
            }
        }
        __half* yl = Yc + (size_t)l * NTOT + (size_t)img * NPIX;
        #pragma unroll
        for (int o = 0; o < 4; ++o) {
            __half2* q = (__half2*)(yl + (size_t)(tileY + 4 * br + o) * HW + tileX + 4 * bc);
            q[0] = __floats2half2_rn(acc[o][0] + bias, acc[o][1] + bias);
            q[1] = __floats2half2_rn(acc[o][2] + bias, acc[o][3] + bias);
        }
    }
}

// ---- rolling Yc prefetch: load layer L's 4x4 fp16 block (8 dwords) ----
// Issued by ALL threads (inactive/out-of-range ones read garbage inside the
// guarded workspace; predicated away at use).
template<int L>
__device__ __forceinline__ void load_yc(
    const __half* __restrict__ ycb, unsigned (&yc)[4][2],
    int tileX, int tileY)
{
    constexpr int NBC = 20 - L;   // per-layer output width / 4
    const int tid = threadIdx.x;
    const int br = tid / NBC, bc = tid - (tid / NBC) * NBC;
    const int gy0 = tileY - 8 + 2 * L + 4 * br;
    const int gx0 = tileX - 8 + 2 * L + 4 * bc;   // always even
    const __half* pl = ycb + (ptrdiff_t)L * ((ptrdiff_t)IMGS * NPIX);
    #pragma unroll
    for (int o = 0; o < 4; ++o) {
        const __half* p = pl + (ptrdiff_t)(gy0 + o) * HW + gx0;
        yc[o][0] = *(const unsigned*)(p);
        yc[o][1] = *(const unsigned*)(p + 2);
    }
}

// ---------------- one x-conv layer, IN-PLACE in a single LDS buffer ----------------
// scale (1/prev_sum) is folded into the L0 weights (conv is linear).
template<int WIN, int HIN, int L, bool LAST>
__device__ __forceinline__ float conv_layer_ip(
    float* __restrict__ buf, const float* __restrict__ Wx, float scale,
    const unsigned (&ycc)[4][2],
    __half* __restrict__ hout, float* __restrict__ fout,
    int img, int tileX, int tileY)
{
    constexpr int WOUT = WIN - 4, HOUT = HIN - 4;
    constexpr int NBC = WOUT / 4, NBR = HOUT / 4, NB = NBC * NBR;
    const int tid = threadIdx.x;
    const bool active = tid < NB;
    const int br = active ? (tid / NBC) : 0;
    const int bc = active ? (tid - br * NBC) : 0;

    // acc2[o][jp] holds output columns {2jp, 2jp+1} of row o
    v2f acc2[4][2] = {};
    if (active) {
        float w[25];
        #pragma unroll
        for (int k = 0; k < 25; ++k) {
            w[k] = Wx[25 * L + k];
            if constexpr (L == 0) w[k] *= scale;   // fold 1/sum into L0 weights
        }

        const float* xp = buf + (4 * br) * SA + 4 * bc;
        #pragma unroll
        for (int di = 0; di < 8; ++di) {
            const v4f a0 = *(const v4f*)(xp + di * SA);       // ds_read_b128
            const v4f a1 = *(const v4f*)(xp + di * SA + 4);   // ds_read_b128
            v2f pr[7];
            pr[0] = __builtin_shufflevector(a0, a0, 0, 1);
            pr[1] = __builtin_shufflevector(a0, a0, 1, 2);
            pr[2] = __builtin_shufflevector(a0, a0, 2, 3);
            pr[3] = __builtin_shufflevector(a0, a1, 3, 4);
            pr[4] = __builtin_shufflevector(a1, a1, 0, 1);
            pr[5] = __builtin_shufflevector(a1, a1, 1, 2);
            pr[6] = __builtin_shufflevector(a1, a1, 2, 3);
            #pragma unroll
            for (int o = 0; o < 4; ++o) {
                const int ki = di - o;
                if (ki >= 0 && ki <= 4) {   // folds at compile time
                    #pragma unroll
                    for (int kj = 0; kj < 5; ++kj) {
                        const float ww = w[ki * 5 + kj];
                        v2f w2; w2.x = ww; w2.y = ww;
                        acc2[o][0] = __builtin_elementwise_fma(pr[kj],     w2, acc2[o][0]);
                        acc2[o][1] = __builtin_elementwise_fma(pr[kj + 2], w2, acc2[o][1]);
                    }
                }
            }
        }
    }

    if constexpr (!LAST) __syncthreads();   // all reads complete before in-place writes

    const int gy0 = tileY - 8 + 2 * L + 4 * br;   // == tileY + 4*br when L==4
    const int gx0 = tileX - 8 + 2 * L + 4 * bc;

    float bsum = 0.0f;
    if (active) {
        if constexpr (LAST) {
            const size_t base = (size_t)img * NPIX;
            #pragma unroll
            for (int o = 0; o < 4; ++o) {
                float2 u = h2tof2(ycc[o][0]);
                float2 t = h2tof2(ycc[o][1]);
                float4 v;
                v.x = fmaxf(acc2[o][0].x + u.x, 0.0f);
                v.y = fmaxf(acc2[o][0].y + u.y, 0.0f);
                v.z = fmaxf(acc2[o][1].x + t.x, 0.0f);
                v.w = fmaxf(acc2[o][1].y + t.y, 0.0f);
                const size_t idx = base + (size_t)(gy0 + o) * HW + gx0;
                if (fout) {                              // iteration 9: fp32 d_out
                    *(float4*)(fout + idx) = v;
                } else {                                 // iterations 0-8: fp16 ping-pong
                    __half2* q = (__half2*)(hout + idx);
                    q[0] = __floats2half2_rn(v.x, v.y);
                    q[1] = __floats2half2_rn(v.z, v.w);
                }
                bsum += (v.x + v.y) + (v.z + v.w);
            }
        } else {
            bool cok[4];
            #pragma unroll
            for (int j = 0; j < 4; ++j) cok[j] = (unsigned)(gx0 + j) < HW;
            #pragma unroll
            for (int o = 0; o < 4; ++o) {
                const bool rok = (unsigned)(gy0 + o) < HW;
                float2 u = h2tof2(ycc[o][0]);
                float2 t = h2tof2(ycc[o][1]);
                v4f v;
                v.x = (rok && cok[0]) ? fmaxf(acc2[o][0].x + u.x, 0.0f) : 0.0f;
                v.y = (rok && cok[1]) ? fmaxf(acc2[o][0].y + u.y, 0.0f) : 0.0f;
                v.z = (rok && cok[2]) ? fmaxf(acc2[o][1].x + t.x, 0.0f) : 0.0f;
                v.w = (rok && cok[3]) ? fmaxf(acc2[o][1].y + t.y, 0.0f) : 0.0f;
                *(v4f*)(buf + (4 * br + o) * SA + 4 * bc) = v;   // ds_write_b128
            }
        }
    }

    if constexpr (!LAST) __syncthreads();   // writes visible before next layer reads
    (void)img;
    return bsum;
}

// ---------------- fused 5-layer iteration kernel (single LDS buffer) ----------------
// Budget model (measured R10/R13): VGPR budget = 256 / min-waves-per-EU.
// (256,8)->32 spill, (256,6)->40 spill at natural 52, (256,4)->64 ok.
// Rolling depth-1 Yc prefetch cuts natural regs by ~24 (40-reg upfront array
// -> 2x8-reg ping-pong); (256,5) budget ~48 >= new natural -> 5 blocks/CU,
// no spill. Verify via WRITE_SIZE (~16.5 MB; spill would balloon it).
__global__ __launch_bounds__(256, 5) void fused5_yc(
    const __half* __restrict__ xin, const float* __restrict__ Wx,
    const __half* __restrict__ Ych, const float* __restrict__ sum_prev,
    __half* __restrict__ hout, float* __restrict__ fout,
    float* __restrict__ sum_out)
{
    __shared__ __align__(16) float Xa[SA * SH];   // 84x52 = 17.5 KB

    const int img = blockIdx.z;
    const int tileX = blockIdx.x * TLW;
    const int tileY = blockIdx.y * TLH;
    const int tid = threadIdx.x;

    const float scale = sum_prev ? (1.0f / sum_prev[0]) : 1.0f;
    const __half* xim = xin + (size_t)img * NPIX;
    const __half* ycb = Ych + (size_t)img * NPIX;

    // rolling Yc prefetch state (8 regs each, ping-pong)
    unsigned ycP[4][2], ycQ[4][2];
    load_yc<0>(ycb, ycP, tileX, tileY);            // layer 0's Yc

    // ---- stage x (fp16 in) with halo 10, pure copy (scale folded into L0 weights) ----
    constexpr int NPAIR = SW * SH / 2;   // 2184
    for (int p = tid; p < NPAIR; p += 256) {
        int row = p / (SW / 2);
        int cp  = p - row * (SW / 2);
        int gr = tileY - 10 + row;
        int gc = tileX - 10 + 2 * cp;
        unsigned u = 0u;
        if (((unsigned)gr < HW) & ((unsigned)gc < HW))
            u = *(const unsigned*)(xim + (size_t)gr * HW + gc);
        float2 f = h2tof2(u);
        v2f fv; fv.x = f.x; fv.y = f.y;
        *(v2f*)&Xa[2 * p] = fv;                         // ds_write_b64
    }
    __syncthreads();

    // rolling schedule: issue layer l+1's loads before layer l's compute;
    // consumed at layer l+1's write phase (<~1000 cy later).
    load_yc<1>(ycb, ycQ, tileX, tileY);
    conv_layer_ip<84, 52, 0, false>(Xa, Wx, scale, ycP, nullptr, nullptr, img, tileX, tileY);
    load_yc<2>(ycb, ycP, tileX, tileY);
    conv_layer_ip<80, 48, 1, false>(Xa, Wx, scale, ycQ, nullptr, nullptr, img, tileX, tileY);
    load_yc<3>(ycb, ycQ, tileX, tileY);
    conv_layer_ip<76, 44, 2, false>(Xa, Wx, scale, ycP, nullptr, nullptr, img, tileX, tileY);
    load_yc<4>(ycb, ycP, tileX, tileY);
    conv_layer_ip<72, 40, 3, false>(Xa, Wx, scale, ycQ, nullptr, nullptr, img, tileX, tileY);
    float bs = conv_layer_ip<68, 36, 4, true>(Xa, Wx, scale, ycP, hout, fout, img, tileX, tileY);

    bs = wave_reduce_sum(bs);
    __shared__ float ssum[4];
    if ((tid & 63) == 0) ssum[tid >> 6] = bs;
    __syncthreads();
    if (tid == 0)
        atomicAdd(sum_out, (ssum[0] + ssum[1]) + (ssum[2] + ssum[3]));
}

__global__ __launch_bounds__(256) void final_scale_raw(
    float4* __restrict__ io, const float* __restrict__ sum9)
{
    const int n4 = NTOT / 4;
    const float s = 1.0f / sum9[0];
    int tid = threadIdx.x + blockIdx.x * 256;
    int stride = gridDim.x * 256;
    for (int i = tid; i < n4; i += stride) {
        float4 v = io[i];
        v.x *= s; v.y *= s; v.z *= s; v.w *= s;
        io[i] = v;
    }
}

// ---------------- fallback: round-2/3 dual-conv fused kernel ----------------
template<int WIN, int HIN, int L, bool LAST>
__device__ __forceinline__ float conv_layer(
    const float* __restrict__ inb, float* __restrict__ outb,
    const float* __restrict__ yb,
    const float* __restrict__ Wx, const float* __restrict__ Wy,
    const float* __restrict__ bx, const float* __restrict__ by,
    float* __restrict__ gout, int img, int tileX, int tileY)
{
    constexpr int WOUT = WIN - 4, HOUT = HIN - 4;
    constexpr int NBC = WOUT / 4, NBR = HOUT / 4, NB = NBC * NBR;
    const int tid = threadIdx.x;
    float bsum = 0.0f;
    if (tid < NB) {
        float wxl[25], wyl[25];
        #pragma unroll
        for (int k = 0; k < 25; ++k) {
            wxl[k] = Wx[25 * L + k];
            wyl[k] = Wy[25 * L + k];
        }
        const float bias = bx[L] + by[L];
        const int br = tid / NBC, bc = tid - (tid / NBC) * NBC;
        const float* xp = inb + (4 * br) * WIN + 4 * bc;
        const float* yp = yb + (4 * br + 2 * L) * 84 + 4 * bc + 2 * L;

        float acc[4][4] = {};
        #pragma unroll
        for (int di = 0; di < 8; ++di) {
            float xr[8], yr[8];
            *(float4*)&xr[0] = *(const float4*)(xp + di * WIN);
            *(float4*)&xr[4] = *(const float4*)(xp + di * WIN + 4);
            if constexpr ((L & 1) == 0) {
                *(float4*)&yr[0] = *(const float4*)(yp + di * 84);
                *(float4*)&yr[4] = *(const float4*)(yp + di * 84 + 4);
            } else {
                *(float2*)&yr[0] = *(const float2*)(yp + di * 84);
                *(float4*)&yr[2] = *(const float4*)(yp + di * 84 + 2);
                *(float2*)&yr[6] = *(const float2*)(yp + di * 84 + 6);
            }
            #pragma unroll
            for (int o = 0; o < 4; ++o) {
                const int ki = di - o;
                if (ki >= 0 && ki <= 4) {
                    #pragma unroll
                    for (int kj = 0; kj < 5; ++kj) {
                        const float wa = wxl[ki * 5 + kj];
                        const float wb = wyl[ki * 5 + kj];
                        #pragma unroll
                        for (int j = 0; j < 4; ++j)
                            acc[o][j] = fmaf(xr[kj + j], wa,
                                        fmaf(yr[kj + j], wb, acc[o][j]));
                    }
                }
            }
        }

        if constexpr (LAST) {
            #pragma unroll
            for (int o = 0; o < 4; ++o) {
                float4 v;
                v.x = fmaxf(acc[o][0] + bias, 0.0f);
                v.y = fmaxf(acc[o][1] + bias, 0.0f);
                v.z = fmaxf(acc[o][2] + bias, 0.0f);
                v.w = fmaxf(acc[o][3] + bias, 0.0f);
                float* g = gout + (size_t)img * NPIX +
                           (size_t)(tileY + 4 * br + o) * HW + tileX + 4 * bc;
                *(float4*)g = v;
                bsum += (v.x + v.y) + (v.z + v.w);
            }
        } else {
            const int gy0 = tileY - 8 + 2 * L + 4 * br;
            const int gx0 = tileX - 8 + 2 * L + 4 * bc;
            bool cok[4];
            #pragma unroll
            for (int j = 0; j < 4; ++j) cok[j] = (unsigned)(gx0 + j) < HW;
            #pragma unroll
            for (int o = 0; o < 4; ++o) {
                const bool rok = (unsigned)(gy0 + o) < HW;
                float4 v;
                v.x = (rok && cok[0]) ? fmaxf(acc[o][0] + bias, 0.0f) : 0.0f;
                v.y = (rok && cok[1]) ? fmaxf(acc[o][1] + bias, 0.0f) : 0.0f;
                v.z = (rok && cok[2]) ? fmaxf(acc[o][2] + bias, 0.0f) : 0.0f;
                v.w = (rok && cok[3]) ? fmaxf(acc[o][3] + bias, 0.0f) : 0.0f;
                *(float4*)(outb + (4 * br + o) * WOUT + 4 * bc) = v;
            }
        }
    }
    (void)img; (void)gout;
    return bsum;
}

__global__ __launch_bounds__(256, 3) void fused5(
    const float* __restrict__ xin, const float* __restrict__ yin,
    const float* __restrict__ Wx, const float* __restrict__ bx,
    const float* __restrict__ Wy, const float* __restrict__ by,
    const float* __restrict__ scale_p,
    float* __restrict__ gout, float* __restrict__ spart)
{
    __shared__ __align__(16) float Xa[84 * 52];
    __shared__ __align__(16) float Xb[80 * 48];
    __shared__ __align__(16) float Yb[84 * 52];

    const int img = blockIdx.z;
    const int tileX = blockIdx.x * TLW;
    const int tileY = blockIdx.y * TLH;
    const int tid = threadIdx.x;

    const float scale = scale_p ? scale_p[0] : 1.0f;
    const float* xim = xin + (size_t)img * NPIX;
    const float* yim = yin + (size_t)img * NPIX;

    constexpr int NPAIR = 84 * 52 / 2;
    for (int p = tid; p < NPAIR; p += 256) {
        int row = p / 42;
        int cp  = p - row * 42;
        int gr = tileY - 10 + row;
        int gc = tileX - 10 + 2 * cp;
        float2 xv = make_float2(0.f, 0.f), yv = make_float2(0.f, 0.f);
        if (((unsigned)gr < HW) & ((unsigned)gc < HW)) {
            xv = *(const float2*)(xim + (size_t)gr * HW + gc);
            yv = *(const float2*)(yim + (size_t)gr * HW + gc);
        }
        Xa[2 * p]     = xv.x * scale;
        Xa[2 * p + 1] = xv.y * scale;
        *(float2*)&Yb[2 * p] = yv;
    }
    __syncthreads();

    conv_layer<84, 52, 0, false>(Xa, Xb, Yb, Wx, Wy, bx, by, nullptr, img, tileX, tileY);
    __syncthreads();
    conv_layer<80, 48, 1, false>(Xb, Xa, Yb, Wx, Wy, bx, by, nullptr, img, tileX, tileY);
    __syncthreads();
    conv_layer<76, 44, 2, false>(Xa, Xb, Yb, Wx, Wy, bx, by, nullptr, img, tileX, tileY);
    __syncthreads();
    conv_layer<72, 40, 3, false>(Xb, Xa, Yb, Wx, Wy, bx, by, nullptr, img, tileX, tileY);
    __syncthreads();
    float bs = conv_layer<68, 36, 4, true>(Xa, nullptr, Yb, Wx, Wy, bx, by, gout, img, tileX, tileY);

    bs = wave_reduce_sum(bs);
    __shared__ float ssum[4];
    if ((tid & 63) == 0) ssum[tid >> 6] = bs;
    __syncthreads();
    if (tid == 0) {
        int b = (blockIdx.z * gridDim.y + blockIdx.y) * gridDim.x + blockIdx.x;
        spart[b] = (ssum[0] + ssum[1]) + (ssum[2] + ssum[3]);
    }
}

__global__ __launch_bounds__(256) void reduce_sum(
    const float* __restrict__ p, int n, float* __restrict__ invS)
{
    float s = 0.0f;
    for (int i = threadIdx.x; i < n; i += 256) s += p[i];
    s = wave_reduce_sum(s);
    __shared__ float sh[4];
    int lane = threadIdx.x & 63, wid = threadIdx.x >> 6;
    if (lane == 0) sh[wid] = s;
    __syncthreads();
    if (threadIdx.x == 0) invS[0] = 1.0f / ((sh[0] + sh[1]) + (sh[2] + sh[3]));
}

__global__ __launch_bounds__(256) void final_scale(
    float4* __restrict__ io, const float* __restrict__ invS)
{
    const int n4 = NTOT / 4;
    const float s = invS[0];
    int tid = threadIdx.x + blockIdx.x * 256;
    int stride = gridDim.x * 256;
    for (int i = tid; i < n4; i += stride) {
        float4 v = io[i];
        v.x *= s; v.y *= s; v.z *= s; v.w *= s;
        io[i] = v;
    }
}

extern "C" void kernel_launch(void* const* d_in, const int* in_sizes, int n_in,
                              void* d_out, int out_size, void* d_ws, size_t ws_size,
                              hipStream_t stream)
{
    const float* x  = (const float*)d_in[0];
    const float* Wx = (const float*)d_in[1];
    const float* bx = (const float*)d_in[2];
    const float* Wy = (const float*)d_in[3];
    const float* by = (const float*)d_in[4];
    float* out = (float*)d_out;
    float* ws  = (float*)d_ws;

    // workspace layout (floats)
    float* sums  = ws;             // [0..9] per-iteration atomic sums (zeroed)
    float* scal  = ws + 12;        // [12]=min, [13]=1/(max-min)
    float* invS  = ws + 16;        // 10 slots (fallback path)
    float* pmin  = ws + 64;        // 1024
    float* pmax  = ws + 64 + 1024;
    float* spart = ws + 4096;      // 4096 (fallback path)
    // fp16 region: y16 | xhA | xhB | Ych (5 planes) | guard
    __half* y16 = (__half*)(ws + 16384);
    __half* xhA = y16 + NTOT;
    __half* xhB = xhA + NTOT;
    __half* Ych = xhB + NTOT;      // 5*NTOT halves

    const size_t needYC = ((size_t)16384 + 4ull * NTOT + 16384) * sizeof(float);

    minmax_partial<<<1024, 256, 0, stream>>>((const float4*)x, pmin, pmax);
    minmax_final<<<1, 256, 0, stream>>>(pmin, pmax, scal, 1024);

    if (ws_size >= needYC) {
        hipMemsetAsync(sums, 0, 10 * sizeof(float), stream);

        dim3 pgrid(HW / PT, HW / PT, IMGS);            // (8, 8, 32)
        prep<<<pgrid, 256, 0, stream>>>(x, scal, bx, Wy, by, y16, Ych);

        dim3 grid(HW / TLW, HW / TLH, IMGS);           // (8, 16, 32)
        const __half* cur = y16;
        for (int it = 0; it < 10; ++it) {
            __half* hdst = (it % 2 == 0) ? xhA : xhB;
            float* fdst = (it == 9) ? out : nullptr;   // last iteration -> fp32 d_out
            const float* sum_prev = (it > 0) ? (sums + (it - 1)) : nullptr;
            fused5_yc<<<grid, 256, 0, stream>>>(cur, Wx, Ych, sum_prev, hdst, fdst, sums + it);
            cur = hdst;
        }
        final_scale_raw<<<2048, 256, 0, stream>>>((float4*)out, sums + 9);
    } else {
        // --- fallback: round-2/3 dual-conv path (fp32 throughout) ---
        float* ybuf = ws + 16384;
        float* xAf  = ybuf + NTOT;
        normalize_k<<<2048, 256, 0, stream>>>((const float4*)x, (float4*)ybuf, scal);
        dim3 grid(HW / TLW, HW / TLH, IMGS);
        const float* cur = ybuf;
        for (int it = 0; it < 10; ++it) {
            float* dst = (it % 2 == 0) ? xAf : out;
            const float* scale_p = (it > 0) ? (invS + (it - 1)) : nullptr;
            fused5<<<grid, 256, 0, stream>>>(cur, ybuf, Wx, bx, Wy, by, scale_p, dst, spart);
            reduce_sum<<<1, 256, 0, stream>>>(spart, 4096, invS + it);
            cur = dst;
        }
        final_scale<<<2048, 256, 0, stream>>>((float4*)out, invS + 9);
    }
}

// Round 15
// 703.391 us; speedup vs baseline: 1.3504x; 1.1083x over previous
//
#include <hip/hip_runtime.h>
#include <hip/hip_fp16.h>

#define HW    512
#define NPIX  (HW*HW)
#define IMGS  32
#define NTOT  (IMGS*NPIX)

// fused-iteration tile: 64x64 output, halo 10 (5 layers x 2)
#define TLW 64
#define TLH 64
#define SW  84   // 64 + 20
#define SH  84   // 64 + 20
#define SA  84   // physical LDS row stride (floats)
#define NTHREADS 512

// prep tile (normalize + Yc precompute): 64x64, halo 2
#define PT  64
#define PS  68

typedef float v2f __attribute__((ext_vector_type(2)));
typedef float v4f __attribute__((ext_vector_type(4)));

__device__ __forceinline__ float wave_reduce_sum(float v) {
    #pragma unroll
    for (int off = 32; off > 0; off >>= 1) v += __shfl_down(v, off);
    return v;
}

__device__ __forceinline__ float2 h2tof2(unsigned u) {
    __half2 h = *reinterpret_cast<const __half2*>(&u);
    return __half22float2(h);
}

// ---------------- prologue: global min-max ----------------
__global__ __launch_bounds__(256) void minmax_partial(
    const float4* __restrict__ x, float* __restrict__ pmin, float* __restrict__ pmax)
{
    const int n4 = NTOT / 4;
    int tid = threadIdx.x + blockIdx.x * 256;
    int stride = gridDim.x * 256;
    float mn = 3.402823466e38f, mx = -3.402823466e38f;
    for (int i = tid; i < n4; i += stride) {
        float4 v = x[i];
        mn = fminf(mn, fminf(fminf(v.x, v.y), fminf(v.z, v.w)));
        mx = fmaxf(mx, fmaxf(fmaxf(v.x, v.y), fmaxf(v.z, v.w)));
    }
    #pragma unroll
    for (int off = 32; off > 0; off >>= 1) {
        mn = fminf(mn, __shfl_down(mn, off));
        mx = fmaxf(mx, __shfl_down(mx, off));
    }
    __shared__ float smn[4], smx[4];
    int lane = threadIdx.x & 63, wid = threadIdx.x >> 6;
    if (lane == 0) { smn[wid] = mn; smx[wid] = mx; }
    __syncthreads();
    if (threadIdx.x == 0) {
        mn = fminf(fminf(smn[0], smn[1]), fminf(smn[2], smn[3]));
        mx = fmaxf(fmaxf(smx[0], smx[1]), fmaxf(smx[2], smx[3]));
        pmin[blockIdx.x] = mn;
        pmax[blockIdx.x] = mx;
    }
}

__global__ __launch_bounds__(256) void minmax_final(
    const float* __restrict__ pmin, const float* __restrict__ pmax,
    float* __restrict__ scal, int nparts)
{
    float mn = 3.402823466e38f, mx = -3.402823466e38f;
    for (int i = threadIdx.x; i < nparts; i += 256) {
        mn = fminf(mn, pmin[i]);
        mx = fmaxf(mx, pmax[i]);
    }
    #pragma unroll
    for (int off = 32; off > 0; off >>= 1) {
        mn = fminf(mn, __shfl_down(mn, off));
        mx = fmaxf(mx, __shfl_down(mx, off));
    }
    __shared__ float smn[4], smx[4];
    int lane = threadIdx.x & 63, wid = threadIdx.x >> 6;
    if (lane == 0) { smn[wid] = mn; smx[wid] = mx; }
    __syncthreads();
    if (threadIdx.x == 0) {
        mn = fminf(fminf(smn[0], smn[1]), fminf(smn[2], smn[3]));
        mx = fmaxf(fmaxf(smx[0], smx[1]), fmaxf(smx[2], smx[3]));
        scal[0] = mn;
        scal[1] = 1.0f / (mx - mn);
    }
}

__global__ __launch_bounds__(256) void normalize_k(
    const float4* __restrict__ x, float4* __restrict__ y, const float* __restrict__ scal)
{
    const int n4 = NTOT / 4;
    float mn = scal[0], inv = scal[1];
    int tid = threadIdx.x + blockIdx.x * 256;
    int stride = gridDim.x * 256;
    for (int i = tid; i < n4; i += stride) {
        float4 v = x[i];
        v.x = (v.x - mn) * inv;
        v.y = (v.y - mn) * inv;
        v.z = (v.z - mn) * inv;
        v.w = (v.w - mn) * inv;
        y[i] = v;
    }
}

// ---- prep: normalize (-> fp16 y16) + precompute Yc[l] = conv(y,Wy[l]) + bx[l]+by[l] (fp16) ----
__global__ __launch_bounds__(256) void prep(
    const float* __restrict__ x, const float* __restrict__ scal,
    const float* __restrict__ bx,
    const float* __restrict__ Wy, const float* __restrict__ by,
    __half* __restrict__ y16, __half* __restrict__ Yc)
{
    __shared__ __align__(16) float ys[PS * PS];   // 68x68 = 18.5 KB

    const int img = blockIdx.z;
    const int tileX = blockIdx.x * PT;
    const int tileY = blockIdx.y * PT;
    const int tid = threadIdx.x;
    const float mn = scal[0], inv = scal[1];
    const float* xim = x + (size_t)img * NPIX;

    // stage normalized y with halo 2; exact 0 outside image (zero padding)
    for (int p = tid; p < PS * PS / 2; p += 256) {
        int row = p / (PS / 2);
        int cp  = p - row * (PS / 2);
        int gr = tileY - 2 + row;
        int gc = tileX - 2 + 2 * cp;
        float a = 0.f, b = 0.f;
        if (((unsigned)gr < HW) & ((unsigned)gc < HW)) {
            float2 v = *(const float2*)(xim + (size_t)gr * HW + gc);
            a = (v.x - mn) * inv;
            b = (v.y - mn) * inv;
        }
        ys[row * PS + 2 * cp]     = a;
        ys[row * PS + 2 * cp + 1] = b;
    }
    __syncthreads();

    // write normalized y tile to global as fp16
    for (int p = tid; p < PT * PT / 2; p += 256) {
        int row = p / (PT / 2);
        int cp  = p - row * (PT / 2);
        float2 v = *(const float2*)&ys[(row + 2) * PS + 2 * cp + 2];
        *(__half2*)(y16 + (size_t)img * NPIX + (size_t)(tileY + row) * HW + tileX + 2 * cp)
            = __floats2half2_rn(v.x, v.y);
    }

    // each thread: 4x4 output block, 5 convs over the staged y window
    const int br = tid >> 4, bc = tid & 15;
    const float* yp = ys + (4 * br) * PS + 4 * bc;

    #pragma unroll
    for (int l = 0; l < 5; ++l) {
        float w[25];
        #pragma unroll
        for (int k = 0; k < 25; ++k) w[k] = Wy[25 * l + k];
        const float bias = bx[l] + by[l];

        float acc[4][4] = {};
        #pragma unroll
        for (int di = 0; di < 8; ++di) {
            float xr[8];
            *(float4*)&xr[0] = *(const float4*)(yp + di * PS);
            *(float4*)&xr[4] = *(const float4*)(yp + di * PS + 4);
            #pragma unroll
            for (int o = 0; o < 4; ++o) {
                const int ki = di - o;
                if (ki >= 0 && ki <= 4) {
                    #pragma unroll
                    for (int kj = 0; kj < 5; ++kj) {
                        const float wa = w[ki * 5 + kj];
                        #pragma unroll
                        for (int j = 0; j < 4; ++j)
                            acc[o][j] = fmaf(xr[kj + j], wa, acc[o][j]);
                    }
                }
            }
        }
        __half* yl = Yc + (size_t)l * NTOT + (size_t)img * NPIX;
        #pragma unroll
        for (int o = 0; o < 4; ++o) {
            __half2* q = (__half2*)(yl + (size_t)(tileY + 4 * br + o) * HW + tileX + 4 * bc);
            q[0] = __floats2half2_rn(acc[o][0] + bias, acc[o][1] + bias);
            q[1] = __floats2half2_rn(acc[o][2] + bias, acc[o][3] + bias);
        }
    }
}

// ---- rolling Yc prefetch: load layer L's 4x4 fp16 block (8 dwords) ----
// tid is clamped to the active range so inactive threads read a safe
// in-bounds dummy (discarded at use).
template<int L>
__device__ __forceinline__ void load_yc(
    const __half* __restrict__ ycb, unsigned (&yc)[4][2],
    int tileX, int tileY)
{
    constexpr int NBC = 20 - L;          // per-layer output width / 4
    constexpr int NB  = NBC * NBC;       // active threads this layer
    const int tid = threadIdx.x;
    const int tt = (tid < NB) ? tid : 0; // clamp: no out-of-guard reads
    const int br = tt / NBC, bc = tt - (tt / NBC) * NBC;
    const int gy0 = tileY - 8 + 2 * L + 4 * br;
    const int gx0 = tileX - 8 + 2 * L + 4 * bc;   // always even
    const __half* pl = ycb + (ptrdiff_t)L * ((ptrdiff_t)IMGS * NPIX);
    #pragma unroll
    for (int o = 0; o < 4; ++o) {
        const __half* p = pl + (ptrdiff_t)(gy0 + o) * HW + gx0;
        yc[o][0] = *(const unsigned*)(p);
        yc[o][1] = *(const unsigned*)(p + 2);
    }
}

// ---------------- one x-conv layer, IN-PLACE in a single LDS buffer ----------------
// scale (1/prev_sum) is folded into the L0 weights (conv is linear).
template<int WIN, int HIN, int L, bool LAST>
__device__ __forceinline__ float conv_layer_ip(
    float* __restrict__ buf, const float* __restrict__ Wx, float scale,
    const unsigned (&ycc)[4][2],
    __half* __restrict__ hout, float* __restrict__ fout,
    int img, int tileX, int tileY)
{
    constexpr int WOUT = WIN - 4, HOUT = HIN - 4;
    constexpr int NBC = WOUT / 4, NBR = HOUT / 4, NB = NBC * NBR;
    const int tid = threadIdx.x;
    const bool active = tid < NB;
    const int br = active ? (tid / NBC) : 0;
    const int bc = active ? (tid - br * NBC) : 0;

    // acc2[o][jp] holds output columns {2jp, 2jp+1} of row o
    v2f acc2[4][2] = {};
    if (active) {
        float w[25];
        #pragma unroll
        for (int k = 0; k < 25; ++k) {
            w[k] = Wx[25 * L + k];
            if constexpr (L == 0) w[k] *= scale;   // fold 1/sum into L0 weights
        }

        const float* xp = buf + (4 * br) * SA + 4 * bc;
        #pragma unroll
        for (int di = 0; di < 8; ++di) {
            const v4f a0 = *(const v4f*)(xp + di * SA);       // ds_read_b128
            const v4f a1 = *(const v4f*)(xp + di * SA + 4);   // ds_read_b128
            v2f pr[7];
            pr[0] = __builtin_shufflevector(a0, a0, 0, 1);
            pr[1] = __builtin_shufflevector(a0, a0, 1, 2);
            pr[2] = __builtin_shufflevector(a0, a0, 2, 3);
            pr[3] = __builtin_shufflevector(a0, a1, 3, 4);
            pr[4] = __builtin_shufflevector(a1, a1, 0, 1);
            pr[5] = __builtin_shufflevector(a1, a1, 1, 2);
            pr[6] = __builtin_shufflevector(a1, a1, 2, 3);
            #pragma unroll
            for (int o = 0; o < 4; ++o) {
                const int ki = di - o;
                if (ki >= 0 && ki <= 4) {   // folds at compile time
                    #pragma unroll
                    for (int kj = 0; kj < 5; ++kj) {
                        const float ww = w[ki * 5 + kj];
                        v2f w2; w2.x = ww; w2.y = ww;
                        acc2[o][0] = __builtin_elementwise_fma(pr[kj],     w2, acc2[o][0]);
                        acc2[o][1] = __builtin_elementwise_fma(pr[kj + 2], w2, acc2[o][1]);
                    }
                }
            }
        }
    }

    if constexpr (!LAST) __syncthreads();   // all reads complete before in-place writes

    const int gy0 = tileY - 8 + 2 * L + 4 * br;   // == tileY + 4*br when L==4
    const int gx0 = tileX - 8 + 2 * L + 4 * bc;

    float bsum = 0.0f;
    if (active) {
        if constexpr (LAST) {
            const size_t base = (size_t)img * NPIX;
            #pragma unroll
            for (int o = 0; o < 4; ++o) {
                float2 u = h2tof2(ycc[o][0]);
                float2 t = h2tof2(ycc[o][1]);
                float4 v;
                v.x = fmaxf(acc2[o][0].x + u.x, 0.0f);
                v.y = fmaxf(acc2[o][0].y + u.y, 0.0f);
                v.z = fmaxf(acc2[o][1].x + t.x, 0.0f);
                v.w = fmaxf(acc2[o][1].y + t.y, 0.0f);
                const size_t idx = base + (size_t)(gy0 + o) * HW + gx0;
                if (fout) {                              // iteration 9: fp32 d_out
                    *(float4*)(fout + idx) = v;
                } else {                                 // iterations 0-8: fp16 ping-pong
                    __half2* q = (__half2*)(hout + idx);
                    q[0] = __floats2half2_rn(v.x, v.y);
                    q[1] = __floats2half2_rn(v.z, v.w);
                }
                bsum += (v.x + v.y) + (v.z + v.w);
            }
        } else {
            bool cok[4];
            #pragma unroll
            for (int j = 0; j < 4; ++j) cok[j] = (unsigned)(gx0 + j) < HW;
            #pragma unroll
            for (int o = 0; o < 4; ++o) {
                const bool rok = (unsigned)(gy0 + o) < HW;
                float2 u = h2tof2(ycc[o][0]);
                float2 t = h2tof2(ycc[o][1]);
                v4f v;
                v.x = (rok && cok[0]) ? fmaxf(acc2[o][0].x + u.x, 0.0f) : 0.0f;
                v.y = (rok && cok[1]) ? fmaxf(acc2[o][0].y + u.y, 0.0f) : 0.0f;
                v.z = (rok && cok[2]) ? fmaxf(acc2[o][1].x + t.x, 0.0f) : 0.0f;
                v.w = (rok && cok[3]) ? fmaxf(acc2[o][1].y + t.y, 0.0f) : 0.0f;
                *(v4f*)(buf + (4 * br + o) * SA + 4 * bc) = v;   // ds_write_b128
            }
        }
    }

    if constexpr (!LAST) __syncthreads();   // writes visible before next layer reads
    (void)img;
    return bsum;
}

// ---------------- fused 5-layer iteration kernel (64x64 tile, 512 threads) ----------------
// 64x64 tile cuts halo-FMA redundancy 1.42x -> 1.273x (the binding VALU floor;
// R11/R14 proved occupancy/barriers non-binding). LDS 84x84 fp32 = 28.2 KB,
// in-place single buffer. No 2nd launch_bounds arg: measured budget model is
// VGPR_budget = 256/arg (R10: arg8->32 spill; R13: arg6->40 spill); default
// behaves like arg4 (budget 64 >= natural ~48-56, no spill).
__global__ __launch_bounds__(NTHREADS) void fused5_yc(
    const __half* __restrict__ xin, const float* __restrict__ Wx,
    const __half* __restrict__ Ych, const float* __restrict__ sum_prev,
    __half* __restrict__ hout, float* __restrict__ fout,
    float* __restrict__ sum_out)
{
    __shared__ __align__(16) float Xa[SA * SH];   // 84x84 = 28.2 KB

    const int img = blockIdx.z;
    const int tileX = blockIdx.x * TLW;
    const int tileY = blockIdx.y * TLH;
    const int tid = threadIdx.x;

    const float scale = sum_prev ? (1.0f / sum_prev[0]) : 1.0f;
    const __half* xim = xin + (size_t)img * NPIX;
    const __half* ycb = Ych + (size_t)img * NPIX;

    // rolling Yc prefetch state (8 regs each, ping-pong)
    unsigned ycP[4][2], ycQ[4][2];
    load_yc<0>(ycb, ycP, tileX, tileY);            // layer 0's Yc

    // ---- stage x (fp16 in) with halo 10, pure copy (scale folded into L0 weights) ----
    constexpr int NPAIR = SW * SH / 2;   // 3528
    for (int p = tid; p < NPAIR; p += NTHREADS) {
        int row = p / (SW / 2);
        int cp  = p - row * (SW / 2);
        int gr = tileY - 10 + row;
        int gc = tileX - 10 + 2 * cp;
        unsigned u = 0u;
        if (((unsigned)gr < HW) & ((unsigned)gc < HW))
            u = *(const unsigned*)(xim + (size_t)gr * HW + gc);
        float2 f = h2tof2(u);
        v2f fv; fv.x = f.x; fv.y = f.y;
        *(v2f*)&Xa[2 * p] = fv;                         // ds_write_b64
    }
    __syncthreads();

    // rolling schedule: issue layer l+1's loads before layer l's compute;
    // consumed at layer l+1's write phase.
    load_yc<1>(ycb, ycQ, tileX, tileY);
    conv_layer_ip<84, 84, 0, false>(Xa, Wx, scale, ycP, nullptr, nullptr, img, tileX, tileY);
    load_yc<2>(ycb, ycP, tileX, tileY);
    conv_layer_ip<80, 80, 1, false>(Xa, Wx, scale, ycQ, nullptr, nullptr, img, tileX, tileY);
    load_yc<3>(ycb, ycQ, tileX, tileY);
    conv_layer_ip<76, 76, 2, false>(Xa, Wx, scale, ycP, nullptr, nullptr, img, tileX, tileY);
    load_yc<4>(ycb, ycP, tileX, tileY);
    conv_layer_ip<72, 72, 3, false>(Xa, Wx, scale, ycQ, nullptr, nullptr, img, tileX, tileY);
    float bs = conv_layer_ip<68, 68, 4, true>(Xa, Wx, scale, ycP, hout, fout, img, tileX, tileY);

    bs = wave_reduce_sum(bs);
    __shared__ float ssum[NTHREADS / 64];
    if ((tid & 63) == 0) ssum[tid >> 6] = bs;
    __syncthreads();
    if (tid == 0) {
        float s = 0.0f;
        #pragma unroll
        for (int i = 0; i < NTHREADS / 64; ++i) s += ssum[i];
        atomicAdd(sum_out, s);
    }
}

__global__ __launch_bounds__(256) void final_scale_raw(
    float4* __restrict__ io, const float* __restrict__ sum9)
{
    const int n4 = NTOT / 4;
    const float s = 1.0f / sum9[0];
    int tid = threadIdx.x + blockIdx.x * 256;
    int stride = gridDim.x * 256;
    for (int i = tid; i < n4; i += stride) {
        float4 v = io[i];
        v.x *= s; v.y *= s; v.z *= s; v.w *= s;
        io[i] = v;
    }
}

// ---------------- fallback: round-2/3 dual-conv fused kernel ----------------
template<int WIN, int HIN, int L, bool LAST>
__device__ __forceinline__ float conv_layer(
    const float* __restrict__ inb, float* __restrict__ outb,
    const float* __restrict__ yb,
    const float* __restrict__ Wx, const float* __restrict__ Wy,
    const float* __restrict__ bx, const float* __restrict__ by,
    float* __restrict__ gout, int img, int tileX, int tileY)
{
    constexpr int WOUT = WIN - 4, HOUT = HIN - 4;
    constexpr int NBC = WOUT / 4, NBR = HOUT / 4, NB = NBC * NBR;
    const int tid = threadIdx.x;
    float bsum = 0.0f;
    if (tid < NB) {
        float wxl[25], wyl[25];
        #pragma unroll
        for (int k = 0; k < 25; ++k) {
            wxl[k] = Wx[25 * L + k];
            wyl[k] = Wy[25 * L + k];
        }
        const float bias = bx[L] + by[L];
        const int br = tid / NBC, bc = tid - (tid / NBC) * NBC;
        const float* xp = inb + (4 * br) * WIN + 4 * bc;
        const float* yp = yb + (4 * br + 2 * L) * 84 + 4 * bc + 2 * L;

        float acc[4][4] = {};
        #pragma unroll
        for (int di = 0; di < 8; ++di) {
            float xr[8], yr[8];
            *(float4*)&xr[0] = *(const float4*)(xp + di * WIN);
            *(float4*)&xr[4] = *(const float4*)(xp + di * WIN + 4);
            if constexpr ((L & 1) == 0) {
                *(float4*)&yr[0] = *(const float4*)(yp + di * 84);
                *(float4*)&yr[4] = *(const float4*)(yp + di * 84 + 4);
            } else {
                *(float2*)&yr[0] = *(const float2*)(yp + di * 84);
                *(float4*)&yr[2] = *(const float4*)(yp + di * 84 + 2);
                *(float2*)&yr[6] = *(const float2*)(yp + di * 84 + 6);
            }
            #pragma unroll
            for (int o = 0; o < 4; ++o) {
                const int ki = di - o;
                if (ki >= 0 && ki <= 4) {
                    #pragma unroll
                    for (int kj = 0; kj < 5; ++kj) {
                        const float wa = wxl[ki * 5 + kj];
                        const float wb = wyl[ki * 5 + kj];
                        #pragma unroll
                        for (int j = 0; j < 4; ++j)
                            acc[o][j] = fmaf(xr[kj + j], wa,
                                        fmaf(yr[kj + j], wb, acc[o][j]));
                    }
                }
            }
        }

        if constexpr (LAST) {
            #pragma unroll
            for (int o = 0; o < 4; ++o) {
                float4 v;
                v.x = fmaxf(acc[o][0] + bias, 0.0f);
                v.y = fmaxf(acc[o][1] + bias, 0.0f);
                v.z = fmaxf(acc[o][2] + bias, 0.0f);
                v.w = fmaxf(acc[o][3] + bias, 0.0f);
                float* g = gout + (size_t)img * NPIX +
                           (size_t)(tileY + 4 * br + o) * HW + tileX + 4 * bc;
                *(float4*)g = v;
                bsum += (v.x + v.y) + (v.z + v.w);
            }
        } else {
            const int gy0 = tileY - 8 + 2 * L + 4 * br;
            const int gx0 = tileX - 8 + 2 * L + 4 * bc;
            bool cok[4];
            #pragma unroll
            for (int j = 0; j < 4; ++j) cok[j] = (unsigned)(gx0 + j) < HW;
            #pragma unroll
            for (int o = 0; o < 4; ++o) {
                const bool rok = (unsigned)(gy0 + o) < HW;
                float4 v;
                v.x = (rok && cok[0]) ? fmaxf(acc[o][0] + bias, 0.0f) : 0.0f;
                v.y = (rok && cok[1]) ? fmaxf(acc[o][1] + bias, 0.0f) : 0.0f;
                v.z = (rok && cok[2]) ? fmaxf(acc[o][2] + bias, 0.0f) : 0.0f;
                v.w = (rok && cok[3]) ? fmaxf(acc[o][3] + bias, 0.0f) : 0.0f;
                *(float4*)(outb + (4 * br + o) * WOUT + 4 * bc) = v;
            }
        }
    }
    (void)img; (void)gout;
    return bsum;
}

__global__ __launch_bounds__(256, 3) void fused5(
    const float* __restrict__ xin, const float* __restrict__ yin,
    const float* __restrict__ Wx, const float* __restrict__ bx,
    const float* __restrict__ Wy, const float* __restrict__ by,
    const float* __restrict__ scale_p,
    float* __restrict__ gout, float* __restrict__ spart)
{
    __shared__ __align__(16) float Xa[84 * 52];
    __shared__ __align__(16) float Xb[80 * 48];
    __shared__ __align__(16) float Yb[84 * 52];

    const int img = blockIdx.z;
    const int tileX = blockIdx.x * 64;
    const int tileY = blockIdx.y * 32;
    const int tid = threadIdx.x;

    const float scale = scale_p ? scale_p[0] : 1.0f;
    const float* xim = xin + (size_t)img * NPIX;
    const float* yim = yin + (size_t)img * NPIX;

    constexpr int NPAIR = 84 * 52 / 2;
    for (int p = tid; p < NPAIR; p += 256) {
        int row = p / 42;
        int cp  = p - row * 42;
        int gr = tileY - 10 + row;
        int gc = tileX - 10 + 2 * cp;
        float2 xv = make_float2(0.f, 0.f), yv = make_float2(0.f, 0.f);
        if (((unsigned)gr < HW) & ((unsigned)gc < HW)) {
            xv = *(const float2*)(xim + (size_t)gr * HW + gc);
            yv = *(const float2*)(yim + (size_t)gr * HW + gc);
        }
        Xa[2 * p]     = xv.x * scale;
        Xa[2 * p + 1] = xv.y * scale;
        *(float2*)&Yb[2 * p] = yv;
    }
    __syncthreads();

    conv_layer<84, 52, 0, false>(Xa, Xb, Yb, Wx, Wy, bx, by, nullptr, img, tileX, tileY);
    __syncthreads();
    conv_layer<80, 48, 1, false>(Xb, Xa, Yb, Wx, Wy, bx, by, nullptr, img, tileX, tileY);
    __syncthreads();
    conv_layer<76, 44, 2, false>(Xa, Xb, Yb, Wx, Wy, bx, by, nullptr, img, tileX, tileY);
    __syncthreads();
    conv_layer<72, 40, 3, false>(Xb, Xa, Yb, Wx, Wy, bx, by, nullptr, img, tileX, tileY);
    __syncthreads();
    float bs = conv_layer<68, 36, 4, true>(Xa, nullptr, Yb, Wx, Wy, bx, by, gout, img, tileX, tileY);

    bs = wave_reduce_sum(bs);
    __shared__ float ssum[4];
    if ((tid & 63) == 0) ssum[tid >> 6] = bs;
    __syncthreads();
    if (tid == 0) {
        int b = (blockIdx.z * gridDim.y + blockIdx.y) * gridDim.x + blockIdx.x;
        spart[b] = (ssum[0] + ssum[1]) + (ssum[2] + ssum[3]);
    }
}

__global__ __launch_bounds__(256) void reduce_sum(
    const float* __restrict__ p, int n, float* __restrict__ invS)
{
    float s = 0.0f;
    for (int i = threadIdx.x; i < n; i += 256) s += p[i];
    s = wave_reduce_sum(s);
    __shared__ float sh[4];
    int lane = threadIdx.x & 63, wid = threadIdx.x >> 6;
    if (lane == 0) sh[wid] = s;
    __syncthreads();
    if (threadIdx.x == 0) invS[0] = 1.0f / ((sh[0] + sh[1]) + (sh[2] + sh[3]));
}

__global__ __launch_bounds__(256) void final_scale(
    float4* __restrict__ io, const float* __restrict__ invS)
{
    const int n4 = NTOT / 4;
    const float s = invS[0];
    int tid = threadIdx.x + blockIdx.x * 256;
    int stride = gridDim.x * 256;
    for (int i = tid; i < n4; i += stride) {
        float4 v = io[i];
        v.x *= s; v.y *= s; v.z *= s; v.w *= s;
        io[i] = v;
    }
}

extern "C" void kernel_launch(void* const* d_in, const int* in_sizes, int n_in,
                              void* d_out, int out_size, void* d_ws, size_t ws_size,
                              hipStream_t stream)
{
    const float* x  = (const float*)d_in[0];
    const float* Wx = (const float*)d_in[1];
    const float* bx = (const float*)d_in[2];
    const float* Wy = (const float*)d_in[3];
    const float* by = (const float*)d_in[4];
    float* out = (float*)d_out;
    float* ws  = (float*)d_ws;

    // workspace layout (floats)
    float* sums  = ws;             // [0..9] per-iteration atomic sums (zeroed)
    float* scal  = ws + 12;        // [12]=min, [13]=1/(max-min)
    float* invS  = ws + 16;        // 10 slots (fallback path)
    float* pmin  = ws + 64;        // 1024
    float* pmax  = ws + 64 + 1024;
    float* spart = ws + 4096;      // 4096 (fallback path)
    // fp16 region: y16 | xhA | xhB | Ych (5 planes) | guard
    __half* y16 = (__half*)(ws + 16384);
    __half* xhA = y16 + NTOT;
    __half* xhB = xhA + NTOT;
    __half* Ych = xhB + NTOT;      // 5*NTOT halves

    const size_t needYC = ((size_t)16384 + 4ull * NTOT + 16384) * sizeof(float);

    minmax_partial<<<1024, 256, 0, stream>>>((const float4*)x, pmin, pmax);
    minmax_final<<<1, 256, 0, stream>>>(pmin, pmax, scal, 1024);

    if (ws_size >= needYC) {
        hipMemsetAsync(sums, 0, 10 * sizeof(float), stream);

        dim3 pgrid(HW / PT, HW / PT, IMGS);            // (8, 8, 32)
        prep<<<pgrid, 256, 0, stream>>>(x, scal, bx, Wy, by, y16, Ych);

        dim3 grid(HW / TLW, HW / TLH, IMGS);           // (8, 8, 32) = 2048 blocks
        const __half* cur = y16;
        for (int it = 0; it < 10; ++it) {
            __half* hdst = (it % 2 == 0) ? xhA : xhB;
            float* fdst = (it == 9) ? out : nullptr;   // last iteration -> fp32 d_out
            const float* sum_prev = (it > 0) ? (sums + (it - 1)) : nullptr;
            fused5_yc<<<grid, NTHREADS, 0, stream>>>(cur, Wx, Ych, sum_prev, hdst, fdst, sums + it);
            cur = hdst;
        }
        final_scale_raw<<<2048, 256, 0, stream>>>((float4*)out, sums + 9);
    } else {
        // --- fallback: round-2/3 dual-conv path (fp32 throughout) ---
        float* ybuf = ws + 16384;
        float* xAf  = ybuf + NTOT;
        normalize_k<<<2048, 256, 0, stream>>>((const float4*)x, (float4*)ybuf, scal);
        dim3 grid(HW / 64, HW / 32, IMGS);
        const float* cur = ybuf;
        for (int it = 0; it < 10; ++it) {
            float* dst = (it % 2 == 0) ? xAf : out;
            const float* scale_p = (it > 0) ? (invS + (it - 1)) : nullptr;
            fused5<<<grid, 256, 0, stream>>>(cur, ybuf, Wx, bx, Wy, by, scale_p, dst, spart);
            reduce_sum<<<1, 256, 0, stream>>>(spart, 4096, invS + it);
            cur = dst;
        }
        final_scale<<<2048, 256, 0, stream>>>((float4*)out, invS + 9);
    }
}

// Round 16
// 695.723 us; speedup vs baseline: 1.3653x; 1.0110x over previous
//
#include <hip/hip_runtime.h>
#include <hip/hip_fp16.h>

#define HW    512
#define NPIX  (HW*HW)
#define IMGS  32
#define NTOT  (IMGS*NPIX)

// fused-iteration tile: 64x64 output, halo 10 (5 layers x 2)
#define TLW 64
#define TLH 64
#define SW  84   // 64 + 20
#define SH  84   // 64 + 20
#define SA  84   // physical LDS row stride (floats)
#define NTHREADS 512

// prep tile (normalize + Yc precompute): 64x64, halo 2
#define PT  64
#define PS  68

typedef float v2f __attribute__((ext_vector_type(2)));
typedef float v4f __attribute__((ext_vector_type(4)));

__device__ __forceinline__ float wave_reduce_sum(float v) {
    #pragma unroll
    for (int off = 32; off > 0; off >>= 1) v += __shfl_down(v, off);
    return v;
}

__device__ __forceinline__ float2 h2tof2(unsigned u) {
    __half2 h = *reinterpret_cast<const __half2*>(&u);
    return __half22float2(h);
}

// ---------------- prologue: global min-max ----------------
__global__ __launch_bounds__(256) void minmax_partial(
    const float4* __restrict__ x, float* __restrict__ pmin, float* __restrict__ pmax)
{
    const int n4 = NTOT / 4;
    int tid = threadIdx.x + blockIdx.x * 256;
    int stride = gridDim.x * 256;
    float mn = 3.402823466e38f, mx = -3.402823466e38f;
    for (int i = tid; i < n4; i += stride) {
        float4 v = x[i];
        mn = fminf(mn, fminf(fminf(v.x, v.y), fminf(v.z, v.w)));
        mx = fmaxf(mx, fmaxf(fmaxf(v.x, v.y), fmaxf(v.z, v.w)));
    }
    #pragma unroll
    for (int off = 32; off > 0; off >>= 1) {
        mn = fminf(mn, __shfl_down(mn, off));
        mx = fmaxf(mx, __shfl_down(mx, off));
    }
    __shared__ float smn[4], smx[4];
    int lane = threadIdx.x & 63, wid = threadIdx.x >> 6;
    if (lane == 0) { smn[wid] = mn; smx[wid] = mx; }
    __syncthreads();
    if (threadIdx.x == 0) {
        mn = fminf(fminf(smn[0], smn[1]), fminf(smn[2], smn[3]));
        mx = fmaxf(fmaxf(smx[0], smx[1]), fmaxf(smx[2], smx[3]));
        pmin[blockIdx.x] = mn;
        pmax[blockIdx.x] = mx;
    }
}

__global__ __launch_bounds__(256) void minmax_final(
    const float* __restrict__ pmin, const float* __restrict__ pmax,
    float* __restrict__ scal, int nparts)
{
    float mn = 3.402823466e38f, mx = -3.402823466e38f;
    for (int i = threadIdx.x; i < nparts; i += 256) {
        mn = fminf(mn, pmin[i]);
        mx = fmaxf(mx, pmax[i]);
    }
    #pragma unroll
    for (int off = 32; off > 0; off >>= 1) {
        mn = fminf(mn, __shfl_down(mn, off));
        mx = fmaxf(mx, __shfl_down(mx, off));
    }
    __shared__ float smn[4], smx[4];
    int lane = threadIdx.x & 63, wid = threadIdx.x >> 6;
    if (lane == 0) { smn[wid] = mn; smx[wid] = mx; }
    __syncthreads();
    if (threadIdx.x == 0) {
        mn = fminf(fminf(smn[0], smn[1]), fminf(smn[2], smn[3]));
        mx = fmaxf(fmaxf(smx[0], smx[1]), fmaxf(smx[2], smx[3]));
        scal[0] = mn;
        scal[1] = 1.0f / (mx - mn);
    }
}

__global__ __launch_bounds__(256) void normalize_k(
    const float4* __restrict__ x, float4* __restrict__ y, const float* __restrict__ scal)
{
    const int n4 = NTOT / 4;
    float mn = scal[0], inv = scal[1];
    int tid = threadIdx.x + blockIdx.x * 256;
    int stride = gridDim.x * 256;
    for (int i = tid; i < n4; i += stride) {
        float4 v = x[i];
        v.x = (v.x - mn) * inv;
        v.y = (v.y - mn) * inv;
        v.z = (v.z - mn) * inv;
        v.w = (v.w - mn) * inv;
        y[i] = v;
    }
}

// ---- prep: normalize (-> fp16 y16) + precompute Yc[l] = conv(y,Wy[l]) + bx[l]+by[l] (fp16) ----
__global__ __launch_bounds__(256) void prep(
    const float* __restrict__ x, const float* __restrict__ scal,
    const float* __restrict__ bx,
    const float* __restrict__ Wy, const float* __restrict__ by,
    __half* __restrict__ y16, __half* __restrict__ Yc)
{
    __shared__ __align__(16) float ys[PS * PS];   // 68x68 = 18.5 KB

    const int img = blockIdx.z;
    const int tileX = blockIdx.x * PT;
    const int tileY = blockIdx.y * PT;
    const int tid = threadIdx.x;
    const float mn = scal[0], inv = scal[1];
    const float* xim = x + (size_t)img * NPIX;

    // stage normalized y with halo 2; exact 0 outside image (zero padding)
    for (int p = tid; p < PS * PS / 2; p += 256) {
        int row = p / (PS / 2);
        int cp  = p - row * (PS / 2);
        int gr = tileY - 2 + row;
        int gc = tileX - 2 + 2 * cp;
        float a = 0.f, b = 0.f;
        if (((unsigned)gr < HW) & ((unsigned)gc < HW)) {
            float2 v = *(const float2*)(xim + (size_t)gr * HW + gc);
            a = (v.x - mn) * inv;
            b = (v.y - mn) * inv;
        }
        ys[row * PS + 2 * cp]     = a;
        ys[row * PS + 2 * cp + 1] = b;
    }
    __syncthreads();

    // write normalized y tile to global as fp16
    for (int p = tid; p < PT * PT / 2; p += 256) {
        int row = p / (PT / 2);
        int cp  = p - row * (PT / 2);
        float2 v = *(const float2*)&ys[(row + 2) * PS + 2 * cp + 2];
        *(__half2*)(y16 + (size_t)img * NPIX + (size_t)(tileY + row) * HW + tileX + 2 * cp)
            = __floats2half2_rn(v.x, v.y);
    }

    // each thread: 4x4 output block, 5 convs over the staged y window
    const int br = tid >> 4, bc = tid & 15;
    const float* yp = ys + (4 * br) * PS + 4 * bc;

    #pragma unroll
    for (int l = 0; l < 5; ++l) {
        float w[25];
        #pragma unroll
        for (int k = 0; k < 25; ++k) w[k] = Wy[25 * l + k];
        const float bias = bx[l] + by[l];

        float acc[4][4] = {};
        #pragma unroll
        for (int di = 0; di < 8; ++di) {
            float xr[8];
            *(float4*)&xr[0] = *(const float4*)(yp + di * PS);
            *(float4*)&xr[4] = *(const float4*)(yp + di * PS + 4);
            #pragma unroll
            for (int o = 0; o < 4; ++o) {
                const int ki = di - o;
                if (ki >= 0 && ki <= 4) {
                    #pragma unroll
                    for (int kj = 0; kj < 5; ++kj) {
                        const float wa = w[ki * 5 + kj];
                        #pragma unroll
                        for (int j = 0; j < 4; ++j)
                            acc[o][j] = fmaf(xr[kj + j], wa, acc[o][j]);
                    }
                }
            }
        }
        __half* yl = Yc + (size_t)l * NTOT + (size_t)img * NPIX;
        #pragma unroll
        for (int o = 0; o < 4; ++o) {
            __half2* q = (__half2*)(yl + (size_t)(tileY + 4 * br + o) * HW + tileX + 4 * bc);
            q[0] = __floats2half2_rn(acc[o][0] + bias, acc[o][1] + bias);
            q[1] = __floats2half2_rn(acc[o][2] + bias, acc[o][3] + bias);
        }
    }
}

// ---- rolling Yc prefetch: load layer L's 4x4 fp16 block (8 dwords) ----
// tid is clamped to the active range so inactive threads read a safe
// in-bounds dummy (discarded at use).
template<int L>
__device__ __forceinline__ void load_yc(
    const __half* __restrict__ ycb, unsigned (&yc)[4][2],
    int tileX, int tileY)
{
    constexpr int NBC = 20 - L;          // per-layer output width / 4
    constexpr int NB  = NBC * NBC;       // active threads this layer
    const int tid = threadIdx.x;
    const int tt = (tid < NB) ? tid : 0; // clamp: no out-of-guard reads
    const int br = tt / NBC, bc = tt - (tt / NBC) * NBC;
    const int gy0 = tileY - 8 + 2 * L + 4 * br;
    const int gx0 = tileX - 8 + 2 * L + 4 * bc;   // always even
    const __half* pl = ycb + (ptrdiff_t)L * ((ptrdiff_t)IMGS * NPIX);
    #pragma unroll
    for (int o = 0; o < 4; ++o) {
        const __half* p = pl + (ptrdiff_t)(gy0 + o) * HW + gx0;
        yc[o][0] = *(const unsigned*)(p);
        yc[o][1] = *(const unsigned*)(p + 2);
    }
}

// ---------------- one x-conv layer, IN-PLACE in a single LDS buffer ----------------
// scale (1/prev_sum) is folded into the L0 weights (conv is linear).
// 2-deep software pipeline on the row loads: di+1's two ds_read_b128 are
// issued before di's FMA block consumes its rows, so the ~120cy LDS latency
// overlaps the ~50cy of FMA per row (occupancy too low to hide it via TLP).
template<int WIN, int HIN, int L, bool LAST>
__device__ __forceinline__ float conv_layer_ip(
    float* __restrict__ buf, const float* __restrict__ Wx, float scale,
    const unsigned (&ycc)[4][2],
    __half* __restrict__ hout, float* __restrict__ fout,
    int img, int tileX, int tileY)
{
    constexpr int WOUT = WIN - 4, HOUT = HIN - 4;
    constexpr int NBC = WOUT / 4, NBR = HOUT / 4, NB = NBC * NBR;
    const int tid = threadIdx.x;
    const bool active = tid < NB;
    const int br = active ? (tid / NBC) : 0;
    const int bc = active ? (tid - br * NBC) : 0;

    // acc2[o][jp] holds output columns {2jp, 2jp+1} of row o
    v2f acc2[4][2] = {};
    if (active) {
        float w[25];
        #pragma unroll
        for (int k = 0; k < 25; ++k) {
            w[k] = Wx[25 * L + k];
            if constexpr (L == 0) w[k] *= scale;   // fold 1/sum into L0 weights
        }

        const float* xp = buf + (4 * br) * SA + 4 * bc;
        // prologue: row 0 in flight
        v4f a0c = *(const v4f*)(xp);              // ds_read_b128
        v4f a1c = *(const v4f*)(xp + 4);          // ds_read_b128
        #pragma unroll
        for (int di = 0; di < 8; ++di) {
            // issue next row's loads BEFORE consuming current row
            v4f a0n = a0c, a1n = a1c;
            if (di < 7) {
                a0n = *(const v4f*)(xp + (di + 1) * SA);
                a1n = *(const v4f*)(xp + (di + 1) * SA + 4);
            }
            v2f pr[7];
            pr[0] = __builtin_shufflevector(a0c, a0c, 0, 1);
            pr[1] = __builtin_shufflevector(a0c, a0c, 1, 2);
            pr[2] = __builtin_shufflevector(a0c, a0c, 2, 3);
            pr[3] = __builtin_shufflevector(a0c, a1c, 3, 4);
            pr[4] = __builtin_shufflevector(a1c, a1c, 0, 1);
            pr[5] = __builtin_shufflevector(a1c, a1c, 1, 2);
            pr[6] = __builtin_shufflevector(a1c, a1c, 2, 3);
            #pragma unroll
            for (int o = 0; o < 4; ++o) {
                const int ki = di - o;
                if (ki >= 0 && ki <= 4) {   // folds at compile time
                    #pragma unroll
                    for (int kj = 0; kj < 5; ++kj) {
                        const float ww = w[ki * 5 + kj];
                        v2f w2; w2.x = ww; w2.y = ww;
                        acc2[o][0] = __builtin_elementwise_fma(pr[kj],     w2, acc2[o][0]);
                        acc2[o][1] = __builtin_elementwise_fma(pr[kj + 2], w2, acc2[o][1]);
                    }
                }
            }
            a0c = a0n; a1c = a1n;
        }
    }

    if constexpr (!LAST) __syncthreads();   // all reads complete before in-place writes

    const int gy0 = tileY - 8 + 2 * L + 4 * br;   // == tileY + 4*br when L==4
    const int gx0 = tileX - 8 + 2 * L + 4 * bc;

    float bsum = 0.0f;
    if (active) {
        if constexpr (LAST) {
            const size_t base = (size_t)img * NPIX;
            #pragma unroll
            for (int o = 0; o < 4; ++o) {
                float2 u = h2tof2(ycc[o][0]);
                float2 t = h2tof2(ycc[o][1]);
                float4 v;
                v.x = fmaxf(acc2[o][0].x + u.x, 0.0f);
                v.y = fmaxf(acc2[o][0].y + u.y, 0.0f);
                v.z = fmaxf(acc2[o][1].x + t.x, 0.0f);
                v.w = fmaxf(acc2[o][1].y + t.y, 0.0f);
                const size_t idx = base + (size_t)(gy0 + o) * HW + gx0;
                if (fout) {                              // iteration 9: fp32 d_out
                    *(float4*)(fout + idx) = v;
                } else {                                 // iterations 0-8: fp16 ping-pong
                    __half2* q = (__half2*)(hout + idx);
                    q[0] = __floats2half2_rn(v.x, v.y);
                    q[1] = __floats2half2_rn(v.z, v.w);
                }
                bsum += (v.x + v.y) + (v.z + v.w);
            }
        } else {
            bool cok[4];
            #pragma unroll
            for (int j = 0; j < 4; ++j) cok[j] = (unsigned)(gx0 + j) < HW;
            #pragma unroll
            for (int o = 0; o < 4; ++o) {
                const bool rok = (unsigned)(gy0 + o) < HW;
                float2 u = h2tof2(ycc[o][0]);
                float2 t = h2tof2(ycc[o][1]);
                v4f v;
                v.x = (rok && cok[0]) ? fmaxf(acc2[o][0].x + u.x, 0.0f) : 0.0f;
                v.y = (rok && cok[1]) ? fmaxf(acc2[o][0].y + u.y, 0.0f) : 0.0f;
                v.z = (rok && cok[2]) ? fmaxf(acc2[o][1].x + t.x, 0.0f) : 0.0f;
                v.w = (rok && cok[3]) ? fmaxf(acc2[o][1].y + t.y, 0.0f) : 0.0f;
                *(v4f*)(buf + (4 * br + o) * SA + 4 * bc) = v;   // ds_write_b128
            }
        }
    }

    if constexpr (!LAST) __syncthreads();   // writes visible before next layer reads
    (void)img;
    return bsum;
}

// ---------------- fused 5-layer iteration kernel (64x64 tile, 512 threads) ----------------
__global__ __launch_bounds__(NTHREADS) void fused5_yc(
    const __half* __restrict__ xin, const float* __restrict__ Wx,
    const __half* __restrict__ Ych, const float* __restrict__ sum_prev,
    __half* __restrict__ hout, float* __restrict__ fout,
    float* __restrict__ sum_out)
{
    __shared__ __align__(16) float Xa[SA * SH];   // 84x84 = 28.2 KB

    const int img = blockIdx.z;
    const int tileX = blockIdx.x * TLW;
    const int tileY = blockIdx.y * TLH;
    const int tid = threadIdx.x;

    const float scale = sum_prev ? (1.0f / sum_prev[0]) : 1.0f;
    const __half* xim = xin + (size_t)img * NPIX;
    const __half* ycb = Ych + (size_t)img * NPIX;

    // rolling Yc prefetch state (8 regs each, ping-pong)
    unsigned ycP[4][2], ycQ[4][2];
    load_yc<0>(ycb, ycP, tileX, tileY);            // layer 0's Yc

    // ---- stage x (fp16 in) with halo 10, pure copy (scale folded into L0 weights) ----
    constexpr int NPAIR = SW * SH / 2;   // 3528
    for (int p = tid; p < NPAIR; p += NTHREADS) {
        int row = p / (SW / 2);
        int cp  = p - row * (SW / 2);
        int gr = tileY - 10 + row;
        int gc = tileX - 10 + 2 * cp;
        unsigned u = 0u;
        if (((unsigned)gr < HW) & ((unsigned)gc < HW))
            u = *(const unsigned*)(xim + (size_t)gr * HW + gc);
        float2 f = h2tof2(u);
        v2f fv; fv.x = f.x; fv.y = f.y;
        *(v2f*)&Xa[2 * p] = fv;                         // ds_write_b64
    }
    __syncthreads();

    // rolling schedule: issue layer l+1's loads before layer l's compute;
    // consumed at layer l+1's write phase.
    load_yc<1>(ycb, ycQ, tileX, tileY);
    conv_layer_ip<84, 84, 0, false>(Xa, Wx, scale, ycP, nullptr, nullptr, img, tileX, tileY);
    load_yc<2>(ycb, ycP, tileX, tileY);
    conv_layer_ip<80, 80, 1, false>(Xa, Wx, scale, ycQ, nullptr, nullptr, img, tileX, tileY);
    load_yc<3>(ycb, ycQ, tileX, tileY);
    conv_layer_ip<76, 76, 2, false>(Xa, Wx, scale, ycP, nullptr, nullptr, img, tileX, tileY);
    load_yc<4>(ycb, ycP, tileX, tileY);
    conv_layer_ip<72, 72, 3, false>(Xa, Wx, scale, ycQ, nullptr, nullptr, img, tileX, tileY);
    float bs = conv_layer_ip<68, 68, 4, true>(Xa, Wx, scale, ycP, hout, fout, img, tileX, tileY);

    bs = wave_reduce_sum(bs);
    __shared__ float ssum[NTHREADS / 64];
    if ((tid & 63) == 0) ssum[tid >> 6] = bs;
    __syncthreads();
    if (tid == 0) {
        float s = 0.0f;
        #pragma unroll
        for (int i = 0; i < NTHREADS / 64; ++i) s += ssum[i];
        atomicAdd(sum_out, s);
    }
}

__global__ __launch_bounds__(256) void final_scale_raw(
    float4* __restrict__ io, const float* __restrict__ sum9)
{
    const int n4 = NTOT / 4;
    const float s = 1.0f / sum9[0];
    int tid = threadIdx.x + blockIdx.x * 256;
    int stride = gridDim.x * 256;
    for (int i = tid; i < n4; i += stride) {
        float4 v = io[i];
        v.x *= s; v.y *= s; v.z *= s; v.w *= s;
        io[i] = v;
    }
}

// ---------------- fallback: round-2/3 dual-conv fused kernel ----------------
template<int WIN, int HIN, int L, bool LAST>
__device__ __forceinline__ float conv_layer(
    const float* __restrict__ inb, float* __restrict__ outb,
    const float* __restrict__ yb,
    const float* __restrict__ Wx, const float* __restrict__ Wy,
    const float* __restrict__ bx, const float* __restrict__ by,
    float* __restrict__ gout, int img, int tileX, int tileY)
{
    constexpr int WOUT = WIN - 4, HOUT = HIN - 4;
    constexpr int NBC = WOUT / 4, NBR = HOUT / 4, NB = NBC * NBR;
    const int tid = threadIdx.x;
    float bsum = 0.0f;
    if (tid < NB) {
        float wxl[25], wyl[25];
        #pragma unroll
        for (int k = 0; k < 25; ++k) {
            wxl[k] = Wx[25 * L + k];
            wyl[k] = Wy[25 * L + k];
        }
        const float bias = bx[L] + by[L];
        const int br = tid / NBC, bc = tid - (tid / NBC) * NBC;
        const float* xp = inb + (4 * br) * WIN + 4 * bc;
        const float* yp = yb + (4 * br + 2 * L) * 84 + 4 * bc + 2 * L;

        float acc[4][4] = {};
        #pragma unroll
        for (int di = 0; di < 8; ++di) {
            float xr[8], yr[8];
            *(float4*)&xr[0] = *(const float4*)(xp + di * WIN);
            *(float4*)&xr[4] = *(const float4*)(xp + di * WIN + 4);
            if constexpr ((L & 1) == 0) {
                *(float4*)&yr[0] = *(const float4*)(yp + di * 84);
                *(float4*)&yr[4] = *(const float4*)(yp + di * 84 + 4);
            } else {
                *(float2*)&yr[0] = *(const float2*)(yp + di * 84);
                *(float4*)&yr[2] = *(const float4*)(yp + di * 84 + 2);
                *(float2*)&yr[6] = *(const float2*)(yp + di * 84 + 6);
            }
            #pragma unroll
            for (int o = 0; o < 4; ++o) {
                const int ki = di - o;
                if (ki >= 0 && ki <= 4) {
                    #pragma unroll
                    for (int kj = 0; kj < 5; ++kj) {
                        const float wa = wxl[ki * 5 + kj];
                        const float wb = wyl[ki * 5 + kj];
                        #pragma unroll
                        for (int j = 0; j < 4; ++j)
                            acc[o][j] = fmaf(xr[kj + j], wa,
                                        fmaf(yr[kj + j], wb, acc[o][j]));
                    }
                }
            }
        }

        if constexpr (LAST) {
            #pragma unroll
            for (int o = 0; o < 4; ++o) {
                float4 v;
                v.x = fmaxf(acc[o][0] + bias, 0.0f);
                v.y = fmaxf(acc[o][1] + bias, 0.0f);
                v.z = fmaxf(acc[o][2] + bias, 0.0f);
                v.w = fmaxf(acc[o][3] + bias, 0.0f);
                float* g = gout + (size_t)img * NPIX +
                           (size_t)(tileY + 4 * br + o) * HW + tileX + 4 * bc;
                *(float4*)g = v;
                bsum += (v.x + v.y) + (v.z + v.w);
            }
        } else {
            const int gy0 = tileY - 8 + 2 * L + 4 * br;
            const int gx0 = tileX - 8 + 2 * L + 4 * bc;
            bool cok[4];
            #pragma unroll
            for (int j = 0; j < 4; ++j) cok[j] = (unsigned)(gx0 + j) < HW;
            #pragma unroll
            for (int o = 0; o < 4; ++o) {
                const bool rok = (unsigned)(gy0 + o) < HW;
                float4 v;
                v.x = (rok && cok[0]) ? fmaxf(acc[o][0] + bias, 0.0f) : 0.0f;
                v.y = (rok && cok[1]) ? fmaxf(acc[o][1] + bias, 0.0f) : 0.0f;
                v.z = (rok && cok[2]) ? fmaxf(acc[o][2] + bias, 0.0f) : 0.0f;
                v.w = (rok && cok[3]) ? fmaxf(acc[o][3] + bias, 0.0f) : 0.0f;
                *(float4*)(outb + (4 * br + o) * WOUT + 4 * bc) = v;
            }
        }
    }
    (void)img; (void)gout;
    return bsum;
}

__global__ __launch_bounds__(256, 3) void fused5(
    const float* __restrict__ xin, const float* __restrict__ yin,
    const float* __restrict__ Wx, const float* __restrict__ bx,
    const float* __restrict__ Wy, const float* __restrict__ by,
    const float* __restrict__ scale_p,
    float* __restrict__ gout, float* __restrict__ spart)
{
    __shared__ __align__(16) float Xa[84 * 52];
    __shared__ __align__(16) float Xb[80 * 48];
    __shared__ __align__(16) float Yb[84 * 52];

    const int img = blockIdx.z;
    const int tileX = blockIdx.x * 64;
    const int tileY = blockIdx.y * 32;
    const int tid = threadIdx.x;

    const float scale = scale_p ? scale_p[0] : 1.0f;
    const float* xim = xin + (size_t)img * NPIX;
    const float* yim = yin + (size_t)img * NPIX;

    constexpr int NPAIR = 84 * 52 / 2;
    for (int p = tid; p < NPAIR; p += 256) {
        int row = p / 42;
        int cp  = p - row * 42;
        int gr = tileY - 10 + row;
        int gc = tileX - 10 + 2 * cp;
        float2 xv = make_float2(0.f, 0.f), yv = make_float2(0.f, 0.f);
        if (((unsigned)gr < HW) & ((unsigned)gc < HW)) {
            xv = *(const float2*)(xim + (size_t)gr * HW + gc);
            yv = *(const float2*)(yim + (size_t)gr * HW + gc);
        }
        Xa[2 * p]     = xv.x * scale;
        Xa[2 * p + 1] = xv.y * scale;
        *(float2*)&Yb[2 * p] = yv;
    }
    __syncthreads();

    conv_layer<84, 52, 0, false>(Xa, Xb, Yb, Wx, Wy, bx, by, nullptr, img, tileX, tileY);
    __syncthreads();
    conv_layer<80, 48, 1, false>(Xb, Xa, Yb, Wx, Wy, bx, by, nullptr, img, tileX, tileY);
    __syncthreads();
    conv_layer<76, 44, 2, false>(Xa, Xb, Yb, Wx, Wy, bx, by, nullptr, img, tileX, tileY);
    __syncthreads();
    conv_layer<72, 40, 3, false>(Xb, Xa, Yb, Wx, Wy, bx, by, nullptr, img, tileX, tileY);
    __syncthreads();
    float bs = conv_layer<68, 36, 4, true>(Xa, nullptr, Yb, Wx, Wy, bx, by, gout, img, tileX, tileY);

    bs = wave_reduce_sum(bs);
    __shared__ float ssum[4];
    if ((tid & 63) == 0) ssum[tid >> 6] = bs;
    __syncthreads();
    if (tid == 0) {
        int b = (blockIdx.z * gridDim.y + blockIdx.y) * gridDim.x + blockIdx.x;
        spart[b] = (ssum[0] + ssum[1]) + (ssum[2] + ssum[3]);
    }
}

__global__ __launch_bounds__(256) void reduce_sum(
    const float* __restrict__ p, int n, float* __restrict__ invS)
{
    float s = 0.0f;
    for (int i = threadIdx.x; i < n; i += 256) s += p[i];
    s = wave_reduce_sum(s);
    __shared__ float sh[4];
    int lane = threadIdx.x & 63, wid = threadIdx.x >> 6;
    if (lane == 0) sh[wid] = s;
    __syncthreads();
    if (threadIdx.x == 0) invS[0] = 1.0f / ((sh[0] + sh[1]) + (sh[2] + sh[3]));
}

__global__ __launch_bounds__(256) void final_scale(
    float4* __restrict__ io, const float* __restrict__ invS)
{
    const int n4 = NTOT / 4;
    const float s = invS[0];
    int tid = threadIdx.x + blockIdx.x * 256;
    int stride = gridDim.x * 256;
    for (int i = tid; i < n4; i += stride) {
        float4 v = io[i];
        v.x *= s; v.y *= s; v.z *= s; v.w *= s;
        io[i] = v;
    }
}

extern "C" void kernel_launch(void* const* d_in, const int* in_sizes, int n_in,
                              void* d_out, int out_size, void* d_ws, size_t ws_size,
                              hipStream_t stream)
{
    const float* x  = (const float*)d_in[0];
    const float* Wx = (const float*)d_in[1];
    const float* bx = (const float*)d_in[2];
    const float* Wy = (const float*)d_in[3];
    const float* by = (const float*)d_in[4];
    float* out = (float*)d_out;
    float* ws  = (float*)d_ws;

    // workspace layout (floats)
    float* sums  = ws;             // [0..9] per-iteration atomic sums (zeroed)
    float* scal  = ws + 12;        // [12]=min, [13]=1/(max-min)
    float* invS  = ws + 16;        // 10 slots (fallback path)
    float* pmin  = ws + 64;        // 1024
    float* pmax  = ws + 64 + 1024;
    float* spart = ws + 4096;      // 4096 (fallback path)
    // fp16 region: y16 | xhA | xhB | Ych (5 planes) | guard
    __half* y16 = (__half*)(ws + 16384);
    __half* xhA = y16 + NTOT;
    __half* xhB = xhA + NTOT;
    __half* Ych = xhB + NTOT;      // 5*NTOT halves

    const size_t needYC = ((size_t)16384 + 4ull * NTOT + 16384) * sizeof(float);

    minmax_partial<<<1024, 256, 0, stream>>>((const float4*)x, pmin, pmax);
    minmax_final<<<1, 256, 0, stream>>>(pmin, pmax, scal, 1024);

    if (ws_size >= needYC) {
        hipMemsetAsync(sums, 0, 10 * sizeof(float), stream);

        dim3 pgrid(HW / PT, HW / PT, IMGS);            // (8, 8, 32)
        prep<<<pgrid, 256, 0, stream>>>(x, scal, bx, Wy, by, y16, Ych);

        dim3 grid(HW / TLW, HW / TLH, IMGS);           // (8, 8, 32) = 2048 blocks
        const __half* cur = y16;
        for (int it = 0; it < 10; ++it) {
            __half* hdst = (it % 2 == 0) ? xhA : xhB;
            float* fdst = (it == 9) ? out : nullptr;   // last iteration -> fp32 d_out
            const float* sum_prev = (it > 0) ? (sums + (it - 1)) : nullptr;
            fused5_yc<<<grid, NTHREADS, 0, stream>>>(cur, Wx, Ych, sum_prev, hdst, fdst, sums + it);
            cur = hdst;
        }
        final_scale_raw<<<2048, 256, 0, stream>>>((float4*)out, sums + 9);
    } else {
        // --- fallback: round-2/3 dual-conv path (fp32 throughout) ---
        float* ybuf = ws + 16384;
        float* xAf  = ybuf + NTOT;
        normalize_k<<<2048, 256, 0, stream>>>((const float4*)x, (float4*)ybuf, scal);
        dim3 grid(HW / 64, HW / 32, IMGS);
        const float* cur = ybuf;
        for (int it = 0; it < 10; ++it) {
            float* dst = (it % 2 == 0) ? xAf : out;
            const float* scale_p = (it > 0) ? (invS + (it - 1)) : nullptr;
            fused5<<<grid, 256, 0, stream>>>(cur, ybuf, Wx, bx, Wy, by, scale_p, dst, spart);
            reduce_sum<<<1, 256, 0, stream>>>(spart, 4096, invS + it);
            cur = dst;
        }
        final_scale<<<2048, 256, 0, stream>>>((float4*)out, invS + 9);
    }
}